// Round 13
// baseline (191.750 us; speedup 1.0000x reference)
//
#include <hip/hip_runtime.h>

typedef unsigned short u16;
typedef unsigned int   u32;
typedef short s16x8 __attribute__((ext_vector_type(8)));   // 8 x bf16 (4 VGPRs)
typedef float f32x4 __attribute__((ext_vector_type(4)));

// ---- workspace layout (bytes); total footprint 34,340,864 (proven safe) ----
#define WS_STATSV 0          // (unused)
#define WS_STATSC 65536      // (unused)
#define WS_WT_VQK 131072     // [512][256] bf16
#define WS_WT_CQK 393216     // [512][64]
#define WS_WT_VV  458752     // [256][256]
#define WS_WT_CV  589824     // [256][64]
#define WS_WT_OV  622592     // [256][256]
#define WS_WT_OC  753664     // [64][256]
#define WS_Q      786432     // [16][2048][128] bf16  (qv|qc per head; Q pre-scaled by log2e/8)
#define WS_K      9175040    // frag-major K: [16 bh][64 t][2 f][4 kc][64 lane][8] bf16 (512KB/bh)
#define WS_VT     17563648   // frag-major V: [16 bh][64 t][8 f8][64 lane][8] bf16 (sigma-permuted kv)
#define WS_OV     25952256   // [8192][256] bf16 attn-out V
#define WS_OC     30146560   // [8192][256] bf16 attn-out C

__device__ __forceinline__ float bf2f(u16 h){
  union { u32 u; float f; } x; x.u = ((u32)h) << 16; return x.f;
}
__device__ __forceinline__ u16 f2bf(float f){
  union { float f; u32 u; } x; x.f = f;
  u32 u = x.u; u += 0x7fffu + ((u >> 16) & 1u);
  return (u16)(u >> 16);
}
__device__ __forceinline__ f32x4 mfma16(s16x8 a, s16x8 b, f32x4 c){
  return __builtin_amdgcn_mfma_f32_16x16x32_bf16(a, b, c, 0, 0, 0);
}
// NOTE (round-12 post-mortem): raw `asm("v_exp_f32")` is a TRANS op whose result
// needs a 1-cycle wait state before consumption; inline asm bypasses the compiler's
// hazard recognizer -> sporadic garbage (absmax 5.5e-2). Reverted to libm exp2f.

// ---------------- k_prep v7: weight transpose ONLY (LN fused into k_proj). 160 blocks. ----
__global__ __launch_bounds__(256) void k_prep(const float* Wvqk, const float* Wcqk,
    const float* Wvv, const float* Wcv, const float* Wov, const float* Woc, char* ws){
  int tb = blockIdx.x;
  const float* src; u16* dst; int K, N, rel;
  if      (tb <  64){ src=Wvqk; dst=(u16*)(ws+WS_WT_VQK); K=256; N=512; rel=tb;     }
  else if (tb <  80){ src=Wcqk; dst=(u16*)(ws+WS_WT_CQK); K=64;  N=512; rel=tb-64;  }
  else if (tb < 112){ src=Wvv;  dst=(u16*)(ws+WS_WT_VV);  K=256; N=256; rel=tb-80;  }
  else if (tb < 120){ src=Wcv;  dst=(u16*)(ws+WS_WT_CV);  K=64;  N=256; rel=tb-112; }
  else if (tb < 152){ src=Wov;  dst=(u16*)(ws+WS_WT_OV);  K=256; N=256; rel=tb-120; }
  else              { src=Woc;  dst=(u16*)(ws+WS_WT_OC);  K=256; N=64;  rel=tb-152; }
  int e = rel*2048 + threadIdx.x*8;
  int k = e / N, n0 = e % N;
  float4 t0 = *(const float4*)(src + e);
  float4 t1 = *(const float4*)(src + e + 4);
  dst[(n0+0)*K + k] = f2bf(t0.x);
  dst[(n0+1)*K + k] = f2bf(t0.y);
  dst[(n0+2)*K + k] = f2bf(t0.z);
  dst[(n0+3)*K + k] = f2bf(t0.w);
  dst[(n0+4)*K + k] = f2bf(t1.x);
  dst[(n0+5)*K + k] = f2bf(t1.y);
  dst[(n0+6)*K + k] = f2bf(t1.z);
  dst[(n0+7)*K + k] = f2bf(t1.w);
}

// ---------------- fused projections v7: in-block LN + GEMM (A from LDS).
// bids [0,128) V-qk 64-row (4 slabs/wave), [128,256) C-qk, [256,384) V-v (2 slabs/wave),
// [384,512) C-v. LN phase: wave w normalizes rows rb+w*16..+15 into padded LDS tile
// (stride 264/72 u16 -> 2-way banks, 16B-aligned) with the EXACT k_prep per-row chain
// (same lane->element map, same shuffle order, same fmaf) -> bit-identical values.
__global__ __launch_bounds__(256) void k_proj(const float* V, const float* C,
    const float* vng, const float* vnb, const float* cng, const float* cnb,
    const float* bvqk, const float* bcqk, const float* rmsv, const float* rmsc,
    const float* bvv, const float* bcv, char* ws){
  __shared__ float ssl[4][4][16];
  __shared__ u16 qst[2][2304];   // Q waves w=0,1: [head2][token16][72]
  __shared__ u16 kst[2][2048];   // K waves w=2,3: [head2][kc2][qK4][cK16][eK8]
  __shared__ u16 Asm[16896];     // LN'd A tile: 64 rows x 264 (V) / x 72 (C)
  int bid = blockIdx.x;
  int tid = threadIdx.x, lane = tid & 63, w = tid >> 6;
  int c = lane & 15, q = lane >> 4;

  bool csd = (bid >> 7) & 1;     // C-side?
  int rb = (bid & 127) * 64;
  int astr = csd ? 72 : 264;

  // ---- LN phase (bit-identical to old k_prep) ----
  if (!csd){
    float4 gg = ((const float4*)vng)[lane];
    float4 bb = ((const float4*)vnb)[lane];
    #pragma unroll 4
    for (int rr=0; rr<16; rr++){
      int row = rb + w*16 + rr;
      float4 v = ((const float4*)(V + row*256))[lane];
      float s = v.x+v.y+v.z+v.w, s2 = v.x*v.x+v.y*v.y+v.z*v.z+v.w*v.w;
      for (int d=1; d<64; d<<=1){ s += __shfl_xor(s,d); s2 += __shfl_xor(s2,d); }
      float m = s*(1.0f/256.0f); float var = s2*(1.0f/256.0f) - m*m; if (var < 0.f) var = 0.f;
      float rstd = rsqrtf(var + 1e-5f), nb = -m*rstd;
      ushort4 pk;
      pk.x = f2bf(fmaf(fmaf(v.x, rstd, nb), gg.x, bb.x));
      pk.y = f2bf(fmaf(fmaf(v.y, rstd, nb), gg.y, bb.y));
      pk.z = f2bf(fmaf(fmaf(v.z, rstd, nb), gg.z, bb.z));
      pk.w = f2bf(fmaf(fmaf(v.w, rstd, nb), gg.w, bb.w));
      *(ushort4*)&Asm[(w*16+rr)*264 + lane*4] = pk;
    }
  } else {
    float cg = cng[lane], cb = cnb[lane];
    #pragma unroll 4
    for (int rr=0; rr<16; rr++){
      int row = rb + w*16 + rr;
      float x = C[row*64 + lane];
      float s = x, s2 = x*x;
      for (int d=1; d<64; d<<=1){ s += __shfl_xor(s,d); s2 += __shfl_xor(s2,d); }
      float m = s*(1.0f/64.0f); float var = s2*(1.0f/64.0f) - m*m; if (var < 0.f) var = 0.f;
      float rstd = rsqrtf(var + 1e-5f);
      float xn = fmaf(fmaf(x, rstd, -m*rstd), cg, cb);
      Asm[(w*16+rr)*72 + lane] = f2bf(xn);
    }
  }
  __syncthreads();

  if (bid < 256){
    int K            = csd ? 64 : 256;
    const u16* Wt    = (const u16*)(ws + (csd ? WS_WT_CQK : WS_WT_VQK));
    const float* bias= csd ? bcqk : bvqk;
    const float* rms = csd ? rmsc : rmsv;
    int dOff         = csd ? 64 : 0;

    int j0 = w * 128;                 // wave = 128-col group of the 512

    f32x4 acc[4][8];
    #pragma unroll
    for (int s=0;s<4;s++)
      #pragma unroll
      for (int f=0; f<8; f++){ f32x4 z = {0.f,0.f,0.f,0.f}; acc[s][f] = z; }

    int nkc = K >> 5;
    for (int kc=0; kc<nkc; kc++){
      int k0 = kc*32 + q*8;
      s16x8 af[4];
      #pragma unroll
      for (int s=0;s<4;s++) af[s] = *(const s16x8*)&Asm[(s*16 + c)*astr + k0];
      #pragma unroll
      for (int f=0; f<8; f++){
        s16x8 bfr = *(const s16x8*)(Wt + (j0 + f*16 + c)*K + k0);
        #pragma unroll
        for (int s=0;s<4;s++) acc[s][f] = mfma16(af[s], bfr, acc[s][f]);
      }
    }

    float ss[4][4];
    #pragma unroll
    for (int s=0;s<4;s++)
      #pragma unroll
      for (int i=0;i<4;i++) ss[s][i] = 0.f;
    float rsv[8];
    #pragma unroll
    for (int f=0; f<8; f++){
      int j = j0 + f*16 + c;
      float bsv = bias[j]; rsv[f] = rms[j];
      #pragma unroll
      for (int s=0;s<4;s++)
        #pragma unroll
        for (int i=0;i<4;i++){ acc[s][f][i] += bsv; ss[s][i] += acc[s][f][i]*acc[s][f][i]; }
    }
    #pragma unroll
    for (int d=1; d<16; d<<=1){
      #pragma unroll
      for (int s=0;s<4;s++)
        #pragma unroll
        for (int i=0;i<4;i++) ss[s][i] += __shfl_xor(ss[s][i], d);
    }
    if (c == 0){
      #pragma unroll
      for (int s=0;s<4;s++)
        #pragma unroll
        for (int i=0;i<4;i++) ssl[w][s][q*4 + i] = ss[s][i];
    }
    __syncthreads();
    float rmsr[4][4];
    #pragma unroll
    for (int s=0;s<4;s++)
      #pragma unroll
      for (int i=0;i<4;i++){
        int rl = q*4 + i;
        float tot = ssl[0][s][rl] + ssl[1][s][rl] + ssl[2][s][rl] + ssl[3][s][rl];
        rmsr[s][i] = rsqrtf(tot * (1.0f/512.0f) + 1e-6f);
      }
    int b_ = rb >> 11;
    if (w < 2){
      // ---- Q: LDS bounce -> coalesced 16B stores. head = w*2 + (f>>2), dd = dOff+(f&3)*16+c
      u16* qs_ = &qst[w][0];
      u16* dstb = (u16*)(ws + WS_Q);
      const float qscale = 0.125f*1.44269504f;
      int headbase = w*2;
      #pragma unroll
      for (int s=0;s<4;s++){
        int n0g = (rb + s*16) & 2047;
        #pragma unroll
        for (int f=0; f<8; f++){
          int hl = f >> 2, dloc = (f&3)*16 + c;
          #pragma unroll
          for (int i=0;i<4;i++)
            qs_[hl*1152 + (q*4+i)*72 + dloc] = f2bf(acc[s][f][i]*rmsr[s][i]*rsv[f]*qscale);
        }
        #pragma unroll
        for (int it=0; it<4; it++){
          int hl = it>>1, token = (it&1)*8 + (lane>>3), dloc = (lane&7)*8;
          uint4 v = *(uint4*)&qs_[hl*1152 + token*72 + dloc];
          *(uint4*)(dstb + ((b_*4 + headbase + hl)*2048 + n0g + token)*128 + dOff + dloc) = v;
        }
      }
    } else {
      // ---- K: LDS bounce in exact frag-major order -> 1KB contiguous per wave-store.
      u16* ks_ = &kst[w-2][0];
      u16* kfb = (u16*)(ws + WS_K);
      int headbase = (w-2)*2;
      int kcOff = dOff >> 5;
      #pragma unroll
      for (int s=0;s<4;s++){
        int n0g = (rb + s*16) & 2047;
        int t = n0g >> 5, fK = (n0g >> 4) & 1;
        #pragma unroll
        for (int f=0; f<8; f++){
          int hl = f >> 2, ddl = (f&3)*16 + c;
          int kcl = ddl >> 5, qK = (ddl >> 3) & 3, eK = ddl & 7;
          #pragma unroll
          for (int i=0;i<4;i++)
            ks_[hl*1024 + kcl*512 + qK*128 + (q*4+i)*8 + eK]
              = f2bf(acc[s][f][i]*rmsr[s][i]*rsv[f]);
        }
        #pragma unroll
        for (int it=0; it<4; it++){
          int hl = it>>1, kcl = it&1;
          uint4 v = *(uint4*)&ks_[hl*1024 + kcl*512 + lane*8];
          *(uint4*)(kfb + (b_*4 + headbase + hl)*262144 + t*4096
                        + (fK*4 + kcOff + kcl)*512 + lane*8) = v;
        }
      }
    }
  } else {
    int K            = csd ? 64 : 256;
    const u16* Wt    = (const u16*)(ws + (csd ? WS_WT_CV : WS_WT_VV));
    const float* bias= csd ? bcv : bvv;
    int dOff         = csd ? 64 : 0;

    int cgp = w & 1, sl2 = w >> 1;     // 2 colgroups(128) x 2 row-halves(32)
    int j0 = cgp * 128;

    f32x4 acc[2][8];
    #pragma unroll
    for (int s=0;s<2;s++)
      #pragma unroll
      for (int f=0; f<8; f++){ f32x4 z = {0.f,0.f,0.f,0.f}; acc[s][f] = z; }

    int nkc = K >> 5;
    for (int kc=0; kc<nkc; kc++){
      int k0 = kc*32 + q*8;
      s16x8 af0 = *(const s16x8*)&Asm[(sl2*32 + c)*astr + k0];
      s16x8 af1 = *(const s16x8*)&Asm[(sl2*32 + 16 + c)*astr + k0];
      #pragma unroll
      for (int f=0; f<8; f++){
        s16x8 bfr = *(const s16x8*)(Wt + (j0 + f*16 + c)*K + k0);
        acc[0][f] = mfma16(af0, bfr, acc[0][f]);
        acc[1][f] = mfma16(af1, bfr, acc[1][f]);
      }
    }
    // V: fragment-major [bh][t][f8][lane(qV,cV)][e], kv sigma-permuted:
    // stored (q,e): e<4 -> token q*4+e ; e>=4 -> token 16+q*4+(e-4)
    u16* vfb = (u16*)(ws + WS_VT);
    #pragma unroll
    for (int s=0;s<2;s++){
      int r = rb + sl2*32 + s*16 + q*4;
      int b_ = r >> 11, n = r & 2047;
      int t = n >> 5, m = n & 31;             // m&3 == 0
      int qV = (m < 16) ? (m >> 2) : ((m >> 2) - 4);
      int e0 = (m < 16) ? 0 : 4;
      #pragma unroll
      for (int f=0; f<8; f++){
        int j = j0 + f*16 + c;
        float bv_ = bias[j];
        int head = j >> 6, dd = (j & 63) + dOff;
        int f8 = dd >> 4, cV = dd & 15;
        ushort4 pk;
        pk.x = f2bf(acc[s][f][0] + bv_); pk.y = f2bf(acc[s][f][1] + bv_);
        pk.z = f2bf(acc[s][f][2] + bv_); pk.w = f2bf(acc[s][f][3] + bv_);
        *(ushort4*)(vfb + (b_*4 + head)*262144 + t*4096 + f8*512 + (qV*16 + cV)*8 + e0) = pk;
      }
    }
  }
}

// ---------------- flash attention v6 (proven 54.1us): zero-LDS, fragment-direct from L2.
// 512 blocks x 4 waves. Wave (g,h): g = Q-subblock (32 rows as 2x16), h = KV half.
// Register double-buffering prefetches tile t+1 while computing t; 2 blocks/CU.
__global__ __launch_bounds__(256, 2) void k_attn(char* ws){
  const u16* Qw = (const u16*)(ws + WS_Q);
  const u16* KF = (const u16*)(ws + WS_K);
  const u16* VF = (const u16*)(ws + WS_VT);
  u16* Ov = (u16*)(ws + WS_OV);
  u16* Oc = (u16*)(ws + WS_OC);
  __shared__ float mg[2][64][67];   // 34,304 B merge buffer (stride 67: conflict-free)

  int bh = blockIdx.x & 15, qb = blockIdx.x >> 4;
  int tid = threadIdx.x, lane = tid & 63, w = tid >> 6;
  int c = lane & 15, q = lane >> 4;
  int g = w & 1, h = w >> 1;
  int qr0 = qb*64 + g*32;

  // Q fragments (rows qr0 + s*16 + c), read-once from global; B-operand of swapped QK^T
  s16x8 qf[2][4];
  #pragma unroll
  for (int s=0;s<2;s++)
    #pragma unroll
    for (int kc=0;kc<4;kc++)
      qf[s][kc] = *(const s16x8*)(Qw + (bh*2048 + qr0 + s*16 + c)*128 + kc*32 + q*8);

  const u16* kb = KF + bh*262144 + h*131072 + lane*8;   // tile stride 4096 u16
  const u16* vb = VF + bh*262144 + h*131072 + lane*8;

  f32x4 o[2][8];
  float lsum[2] = {0.f, 0.f};
  #pragma unroll
  for (int s=0;s<2;s++)
    #pragma unroll
    for (int f8=0;f8<8;f8++){ f32x4 z = {0.f,0.f,0.f,0.f}; o[s][f8] = z; }

  s16x8 kA[2][4], vA[8], kB[2][4], vB[8];

  auto loadT = [&](s16x8 (&kf)[2][4], s16x8 (&vf)[8], int tt){
    const u16* kt = kb + tt*4096;
    const u16* vt = vb + tt*4096;
    #pragma unroll
    for (int f=0;f<2;f++)
      #pragma unroll
      for (int kc=0;kc<4;kc++)
        kf[f][kc] = *(const s16x8*)(kt + (f*4+kc)*512);
    #pragma unroll
    for (int f8=0;f8<8;f8++)
      vf[f8] = *(const s16x8*)(vt + f8*512);
  };

  auto comp = [&](const s16x8 (&kf)[2][4], const s16x8 (&vf)[8]){
    // swapped QK^T: A=K, B=Q  ->  lane (c,q) holds S[qrow=c][kv=f*16+q*4+i]
    f32x4 sfr[2][2];
    #pragma unroll
    for (int s=0;s<2;s++)
      #pragma unroll
      for (int f=0;f<2;f++){ f32x4 z = {0.f,0.f,0.f,0.f}; sfr[s][f] = z; }
    #pragma unroll
    for (int s=0;s<2;s++)
      #pragma unroll
      for (int f=0;f<2;f++)
        #pragma unroll
        for (int kc=0;kc<4;kc++)
          sfr[s][f] = mfma16(kf[f][kc], qf[s][kc], sfr[s][f]);

    #pragma unroll
    for (int s=0;s<2;s++){
      float p0 = exp2f(sfr[s][0][0]), p1 = exp2f(sfr[s][0][1]);
      float p2 = exp2f(sfr[s][0][2]), p3 = exp2f(sfr[s][0][3]);
      float p4 = exp2f(sfr[s][1][0]), p5 = exp2f(sfr[s][1][1]);
      float p6 = exp2f(sfr[s][1][2]), p7 = exp2f(sfr[s][1][3]);
      lsum[s] += ((p0+p1)+(p2+p3)) + ((p4+p5)+(p6+p7));
      union { u32 u[4]; s16x8 v; } pa;
      pa.u[0] = (u32)f2bf(p0) | ((u32)f2bf(p1) << 16);
      pa.u[1] = (u32)f2bf(p2) | ((u32)f2bf(p3) << 16);
      pa.u[2] = (u32)f2bf(p4) | ((u32)f2bf(p5) << 16);
      pa.u[3] = (u32)f2bf(p6) | ((u32)f2bf(p7) << 16);
      #pragma unroll
      for (int f8=0;f8<8;f8++)
        o[s][f8] = mfma16(pa.v, vf[f8], o[s][f8]);
    }
  };

  loadT(kA, vA, 0);
  for (int tt=0; tt<32; tt+=2){
    loadT(kB, vB, tt+1);
    comp(kA, vA);
    if (tt+2 < 32) loadT(kA, vA, tt+2);
    comp(kB, vB);
  }

  // ---- merge the two KV halves (f32, via LDS) ----
  __syncthreads();
  if (h == 1){
    float* d = &mg[g][lane][0];
    #pragma unroll
    for (int s=0;s<2;s++)
      #pragma unroll
      for (int f8=0;f8<8;f8++)
        #pragma unroll
        for (int i=0;i<4;i++) d[(s*8+f8)*4 + i] = o[s][f8][i];
    d[64] = lsum[0]; d[65] = lsum[1];
  }
  __syncthreads();
  if (h == 0){
    float* d = &mg[g][lane][0];
    #pragma unroll
    for (int s=0;s<2;s++)
      #pragma unroll
      for (int f8=0;f8<8;f8++)
        #pragma unroll
        for (int i=0;i<4;i++) o[s][f8][i] += d[(s*8+f8)*4 + i];
    lsum[0] += d[64]; lsum[1] += d[65];

    // full row sums: partials live across q-groups -> reduce over lanes ^16, ^32
    #pragma unroll
    for (int s=0;s<2;s++){
      lsum[s] += __shfl_xor(lsum[s], 16);
      lsum[s] += __shfl_xor(lsum[s], 32);
    }

    int b_ = bh >> 2, hh = bh & 3;
    #pragma unroll
    for (int s=0;s<2;s++){
      float inv[4];
      #pragma unroll
      for (int i=0;i<4;i++) inv[i] = 1.0f/__shfl(lsum[s], q*4 + i);  // row q*4+i total
      #pragma unroll
      for (int f8=0;f8<8;f8++){
        int col = f8*16 + c;
        u16* dst = (col < 64) ? Ov : Oc;
        int ddim = col & 63;
        #pragma unroll
        for (int i=0;i<4;i++){
          int n = qr0 + s*16 + q*4 + i;
          dst[(b_*2048 + n)*256 + hh*64 + ddim] = f2bf(o[s][f8][i]*inv[i]);
        }
      }
    }
  }
}

// ---------------- fused output projections v4: deeper amortization.
// bids [0,128) N=256 64-row blocks (4 slabs/wave x 64-col groups);
// [128,192) N=64 128-row blocks (2 slabs/wave).
__global__ __launch_bounds__(256) void k_out(const u16* Av, const u16* Wtv, const float* bv,
                                             const u16* Ac, const u16* Wtc, const float* bc,
                                             float* out){
  int bid = blockIdx.x;
  int tid = threadIdx.x, lane = tid & 63, w = tid >> 6;
  int c = lane & 15, q = lane >> 4;
  if (bid < 128){
    int rb = bid * 64;
    int j0 = w * 64;
    f32x4 acc[4][4];
    #pragma unroll
    for (int s=0;s<4;s++)
      #pragma unroll
      for (int f=0; f<4; f++){ f32x4 z = {0.f,0.f,0.f,0.f}; acc[s][f] = z; }
    for (int kc=0; kc<8; kc++){
      int k0 = kc*32 + q*8;
      s16x8 af[4];
      #pragma unroll
      for (int s=0;s<4;s++) af[s] = *(const s16x8*)(Av + (rb + s*16 + c)*256 + k0);
      #pragma unroll
      for (int f=0; f<4; f++){
        s16x8 bfr = *(const s16x8*)(Wtv + (j0 + f*16 + c)*256 + k0);
        #pragma unroll
        for (int s=0;s<4;s++) acc[s][f] = mfma16(af[s], bfr, acc[s][f]);
      }
    }
    #pragma unroll
    for (int f=0; f<4; f++){
      int j = j0 + f*16 + c;
      float bb = bv[j];
      #pragma unroll
      for (int s=0;s<4;s++)
        #pragma unroll
        for (int i=0;i<4;i++)
          out[(rb + s*16 + q*4 + i)*256 + j] = acc[s][f][i] + bb;
    }
  } else {
    int rb = (bid - 128) * 128;
    int r0 = rb + w*32;
    f32x4 acc[2][4];
    #pragma unroll
    for (int s=0;s<2;s++)
      #pragma unroll
      for (int f=0; f<4; f++){ f32x4 z = {0.f,0.f,0.f,0.f}; acc[s][f] = z; }
    for (int kc=0; kc<8; kc++){
      int k0 = kc*32 + q*8;
      s16x8 af0 = *(const s16x8*)(Ac + (r0 + c)*256 + k0);
      s16x8 af1 = *(const s16x8*)(Ac + (r0 + 16 + c)*256 + k0);
      #pragma unroll
      for (int f=0; f<4; f++){
        s16x8 bfr = *(const s16x8*)(Wtc + (f*16 + c)*256 + k0);
        acc[0][f] = mfma16(af0, bfr, acc[0][f]);
        acc[1][f] = mfma16(af1, bfr, acc[1][f]);
      }
    }
    float* oc = out + 2097152;
    #pragma unroll
    for (int f=0; f<4; f++){
      int j = f*16 + c;
      float bb = bc[j];
      #pragma unroll
      for (int s=0;s<2;s++)
        #pragma unroll
        for (int i=0;i<4;i++)
          oc[(r0 + s*16 + q*4 + i)*64 + j] = acc[s][f][i] + bb;
    }
  }
}

extern "C" void kernel_launch(void* const* d_in, const int* in_sizes, int n_in,
                              void* d_out, int out_size, void* d_ws, size_t ws_size,
                              hipStream_t stream){
  (void)in_sizes; (void)n_in; (void)out_size; (void)ws_size;
  const float* V    = (const float*)d_in[0];
  const float* C    = (const float*)d_in[1];
  const float* vng  = (const float*)d_in[2];
  const float* vnb  = (const float*)d_in[3];
  const float* cng  = (const float*)d_in[4];
  const float* cnb  = (const float*)d_in[5];
  const float* Wvqk = (const float*)d_in[6];
  const float* bvqk = (const float*)d_in[7];
  const float* rmsv = (const float*)d_in[8];
  const float* Wcqk = (const float*)d_in[9];
  const float* bcqk = (const float*)d_in[10];
  const float* rmsc = (const float*)d_in[11];
  const float* Wvv  = (const float*)d_in[12];
  const float* bvv  = (const float*)d_in[13];
  const float* Wcv  = (const float*)d_in[14];
  const float* bcv  = (const float*)d_in[15];
  const float* Wov  = (const float*)d_in[16];
  const float* bov  = (const float*)d_in[17];
  const float* Woc  = (const float*)d_in[18];
  const float* boc  = (const float*)d_in[19];
  char* ws = (char*)d_ws;
  float* out = (float*)d_out;

  k_prep<<<160, 256, 0, stream>>>(Wvqk, Wcqk, Wvv, Wcv, Wov, Woc, ws);
  k_proj<<<512, 256, 0, stream>>>(V, C, vng, vnb, cng, cnb,
                                  bvqk, bcqk, rmsv, rmsc, bvv, bcv, ws);
  k_attn<<<512, 256, 0, stream>>>(ws);
  k_out<<<192, 256, 0, stream>>>((const u16*)(ws + WS_OV), (const u16*)(ws + WS_WT_OV), bov,
                                 (const u16*)(ws + WS_OC), (const u16*)(ws + WS_WT_OC), boc,
                                 out);
}

// Round 14
// 190.986 us; speedup vs baseline: 1.0040x; 1.0040x over previous
//
#include <hip/hip_runtime.h>

typedef unsigned short u16;
typedef unsigned int   u32;
typedef short s16x8 __attribute__((ext_vector_type(8)));   // 8 x bf16 (4 VGPRs)
typedef float f32x4 __attribute__((ext_vector_type(4)));

// ---- workspace layout (bytes); total footprint 34,340,864 (proven safe) ----
#define WS_STATSV 0          // (unused)
#define WS_STATSC 65536      // (unused)
#define WS_WT_VQK 131072     // [512][256] bf16
#define WS_WT_CQK 393216     // [512][64]
#define WS_WT_VV  458752     // [256][256]
#define WS_WT_CV  589824     // [256][64]
#define WS_WT_OV  622592     // [256][256]
#define WS_WT_OC  753664     // [64][256]
#define WS_Q      786432     // [16][2048][128] bf16  (qv|qc per head; Q pre-scaled by log2e/8)
#define WS_K      9175040    // frag-major K: [16 bh][64 t][2 f][4 kc][64 lane][8] bf16 (512KB/bh)
#define WS_VT     17563648   // frag-major V: [16 bh][64 t][8 f8][64 lane][8] bf16 (sigma-permuted kv)
#define WS_OV     25952256   // [8192][256] bf16 attn-out V  (pre-attn: Vn, LN'd V bf16 [8192][256])
#define WS_OC     30146560   // [8192][256] bf16 attn-out C  (pre-attn: Cn, LN'd C bf16 [8192][64])

__device__ __forceinline__ float bf2f(u16 h){
  union { u32 u; float f; } x; x.u = ((u32)h) << 16; return x.f;
}
__device__ __forceinline__ u16 f2bf(float f){
  union { float f; u32 u; } x; x.f = f;
  u32 u = x.u; u += 0x7fffu + ((u >> 16) & 1u);
  return (u16)(u >> 16);
}
__device__ __forceinline__ f32x4 mfma16(s16x8 a, s16x8 b, f32x4 c){
  return __builtin_amdgcn_mfma_f32_16x16x32_bf16(a, b, c, 0, 0, 0);
}

// ---------------- fused: LN stats+normalize (bids 0..4095) + weight transpose (4096..4255) ----
// (round-13 post-mortem: LN fused into k_proj was correct but +6us — LN serialized in front
// of the GEMM at 2 blocks/CU. Reverted to this high-occupancy separate-pass version.)
__global__ __launch_bounds__(256) void k_prep(const float* V, const float* C,
    const float* vng, const float* vnb, const float* cng, const float* cnb,
    const float* Wvqk, const float* Wcqk, const float* Wvv, const float* Wcv,
    const float* Wov, const float* Woc, char* ws){
  int bid = blockIdx.x;
  if (bid < 4096){
    int wid = threadIdx.x >> 6, lane = threadIdx.x & 63;
    if (bid < 2048){
      int row = bid*4 + wid;
      const float4* p = (const float4*)(V + row*256);
      float4 v = p[lane];
      float s = v.x+v.y+v.z+v.w, s2 = v.x*v.x+v.y*v.y+v.z*v.z+v.w*v.w;
      for (int d=1; d<64; d<<=1){ s += __shfl_xor(s,d); s2 += __shfl_xor(s2,d); }
      float m = s*(1.0f/256.0f); float var = s2*(1.0f/256.0f) - m*m; if (var < 0.f) var = 0.f;
      float rstd = rsqrtf(var + 1e-5f), nb = -m*rstd;
      float4 gg = ((const float4*)vng)[lane];
      float4 bb = ((const float4*)vnb)[lane];
      ushort4 pk;
      pk.x = f2bf(fmaf(fmaf(v.x, rstd, nb), gg.x, bb.x));
      pk.y = f2bf(fmaf(fmaf(v.y, rstd, nb), gg.y, bb.y));
      pk.z = f2bf(fmaf(fmaf(v.z, rstd, nb), gg.z, bb.z));
      pk.w = f2bf(fmaf(fmaf(v.w, rstd, nb), gg.w, bb.w));
      *(ushort4*)((u16*)(ws + WS_OV) + row*256 + lane*4) = pk;
    } else {
      int row = (bid-2048)*4 + wid;
      float x = C[row*64 + lane];
      float s = x, s2 = x*x;
      for (int d=1; d<64; d<<=1){ s += __shfl_xor(s,d); s2 += __shfl_xor(s2,d); }
      float m = s*(1.0f/64.0f); float var = s2*(1.0f/64.0f) - m*m; if (var < 0.f) var = 0.f;
      float rstd = rsqrtf(var + 1e-5f);
      float xn = fmaf(fmaf(x, rstd, -m*rstd), cng[lane], cnb[lane]);
      ((u16*)(ws + WS_OC))[row*64 + lane] = f2bf(xn);
    }
  } else {
    int tb = bid - 4096;
    const float* src; u16* dst; int K, N, rel;
    if      (tb <  64){ src=Wvqk; dst=(u16*)(ws+WS_WT_VQK); K=256; N=512; rel=tb;     }
    else if (tb <  80){ src=Wcqk; dst=(u16*)(ws+WS_WT_CQK); K=64;  N=512; rel=tb-64;  }
    else if (tb < 112){ src=Wvv;  dst=(u16*)(ws+WS_WT_VV);  K=256; N=256; rel=tb-80;  }
    else if (tb < 120){ src=Wcv;  dst=(u16*)(ws+WS_WT_CV);  K=64;  N=256; rel=tb-112; }
    else if (tb < 152){ src=Wov;  dst=(u16*)(ws+WS_WT_OV);  K=256; N=256; rel=tb-120; }
    else              { src=Woc;  dst=(u16*)(ws+WS_WT_OC);  K=256; N=64;  rel=tb-152; }
    int e = rel*2048 + threadIdx.x*8;
    int k = e / N, n0 = e % N;
    float4 t0 = *(const float4*)(src + e);
    float4 t1 = *(const float4*)(src + e + 4);
    dst[(n0+0)*K + k] = f2bf(t0.x);
    dst[(n0+1)*K + k] = f2bf(t0.y);
    dst[(n0+2)*K + k] = f2bf(t0.z);
    dst[(n0+3)*K + k] = f2bf(t0.w);
    dst[(n0+4)*K + k] = f2bf(t1.x);
    dst[(n0+5)*K + k] = f2bf(t1.y);
    dst[(n0+6)*K + k] = f2bf(t1.z);
    dst[(n0+7)*K + k] = f2bf(t1.w);
  }
}

// ---------------- fused projections v6: deeper B-fragment amortization (proven 185.7 config).
// bids [0,128) V-qk 64-row (4 slabs/wave), [128,256) C-qk 64-row,
//      [256,384) V-v 64-row (2 slabs/wave), [384,512) C-v 64-row.
__global__ __launch_bounds__(256) void k_proj(const float* bvqk, const float* bcqk,
    const float* rmsv, const float* rmsc, const float* bvv, const float* bcv, char* ws){
  __shared__ float ssl[4][4][16];
  __shared__ u16 qst[2][2304];   // Q waves w=0,1: [head2][token16][72]
  __shared__ u16 kst[2][2048];   // K waves w=2,3: [head2][kc2][qK4][cK16][eK8]
  int bid = blockIdx.x;
  int tid = threadIdx.x, lane = tid & 63, w = tid >> 6;
  int c = lane & 15, q = lane >> 4;

  if (bid < 256){
    bool csd = bid >= 128;
    int rb = (bid & 127) * 64;
    const u16* An    = (const u16*)(ws + (csd ? WS_OC : WS_OV));   // Cn / Vn
    int K            = csd ? 64 : 256;
    const u16* Wt    = (const u16*)(ws + (csd ? WS_WT_CQK : WS_WT_VQK));
    const float* bias= csd ? bcqk : bvqk;
    const float* rms = csd ? rmsc : rmsv;
    int dOff         = csd ? 64 : 0;

    int j0 = w * 128;                 // wave = 128-col group of the 512

    f32x4 acc[4][8];
    #pragma unroll
    for (int s=0;s<4;s++)
      #pragma unroll
      for (int f=0; f<8; f++){ f32x4 z = {0.f,0.f,0.f,0.f}; acc[s][f] = z; }

    int nkc = K >> 5;
    for (int kc=0; kc<nkc; kc++){
      int k0 = kc*32 + q*8;
      s16x8 af[4];
      #pragma unroll
      for (int s=0;s<4;s++) af[s] = *(const s16x8*)(An + (rb + s*16 + c)*K + k0);
      #pragma unroll
      for (int f=0; f<8; f++){
        s16x8 bfr = *(const s16x8*)(Wt + (j0 + f*16 + c)*K + k0);
        #pragma unroll
        for (int s=0;s<4;s++) acc[s][f] = mfma16(af[s], bfr, acc[s][f]);
      }
    }

    float ss[4][4];
    #pragma unroll
    for (int s=0;s<4;s++)
      #pragma unroll
      for (int i=0;i<4;i++) ss[s][i] = 0.f;
    float rsv[8];
    #pragma unroll
    for (int f=0; f<8; f++){
      int j = j0 + f*16 + c;
      float bsv = bias[j]; rsv[f] = rms[j];
      #pragma unroll
      for (int s=0;s<4;s++)
        #pragma unroll
        for (int i=0;i<4;i++){ acc[s][f][i] += bsv; ss[s][i] += acc[s][f][i]*acc[s][f][i]; }
    }
    #pragma unroll
    for (int d=1; d<16; d<<=1){
      #pragma unroll
      for (int s=0;s<4;s++)
        #pragma unroll
        for (int i=0;i<4;i++) ss[s][i] += __shfl_xor(ss[s][i], d);
    }
    if (c == 0){
      #pragma unroll
      for (int s=0;s<4;s++)
        #pragma unroll
        for (int i=0;i<4;i++) ssl[w][s][q*4 + i] = ss[s][i];
    }
    __syncthreads();
    float rmsr[4][4];
    #pragma unroll
    for (int s=0;s<4;s++)
      #pragma unroll
      for (int i=0;i<4;i++){
        int rl = q*4 + i;
        float tot = ssl[0][s][rl] + ssl[1][s][rl] + ssl[2][s][rl] + ssl[3][s][rl];
        rmsr[s][i] = rsqrtf(tot * (1.0f/512.0f) + 1e-6f);
      }
    int b_ = rb >> 11;
    if (w < 2){
      // ---- Q: LDS bounce -> coalesced 16B stores. head = w*2 + (f>>2), dd = dOff+(f&3)*16+c
      u16* qs_ = &qst[w][0];
      u16* dstb = (u16*)(ws + WS_Q);
      const float qscale = 0.125f*1.44269504f;
      int headbase = w*2;
      #pragma unroll
      for (int s=0;s<4;s++){
        int n0g = (rb + s*16) & 2047;
        #pragma unroll
        for (int f=0; f<8; f++){
          int hl = f >> 2, dloc = (f&3)*16 + c;
          #pragma unroll
          for (int i=0;i<4;i++)
            qs_[hl*1152 + (q*4+i)*72 + dloc] = f2bf(acc[s][f][i]*rmsr[s][i]*rsv[f]*qscale);
        }
        #pragma unroll
        for (int it=0; it<4; it++){
          int hl = it>>1, token = (it&1)*8 + (lane>>3), dloc = (lane&7)*8;
          uint4 v = *(uint4*)&qs_[hl*1152 + token*72 + dloc];
          *(uint4*)(dstb + ((b_*4 + headbase + hl)*2048 + n0g + token)*128 + dOff + dloc) = v;
        }
      }
    } else {
      // ---- K: LDS bounce in exact frag-major order -> 1KB contiguous per wave-store.
      u16* ks_ = &kst[w-2][0];
      u16* kfb = (u16*)(ws + WS_K);
      int headbase = (w-2)*2;
      int kcOff = dOff >> 5;
      #pragma unroll
      for (int s=0;s<4;s++){
        int n0g = (rb + s*16) & 2047;
        int t = n0g >> 5, fK = (n0g >> 4) & 1;
        #pragma unroll
        for (int f=0; f<8; f++){
          int hl = f >> 2, ddl = (f&3)*16 + c;
          int kcl = ddl >> 5, qK = (ddl >> 3) & 3, eK = ddl & 7;
          #pragma unroll
          for (int i=0;i<4;i++)
            ks_[hl*1024 + kcl*512 + qK*128 + (q*4+i)*8 + eK]
              = f2bf(acc[s][f][i]*rmsr[s][i]*rsv[f]);
        }
        #pragma unroll
        for (int it=0; it<4; it++){
          int hl = it>>1, kcl = it&1;
          uint4 v = *(uint4*)&ks_[hl*1024 + kcl*512 + lane*8];
          *(uint4*)(kfb + (b_*4 + headbase + hl)*262144 + t*4096
                        + (fK*4 + kcOff + kcl)*512 + lane*8) = v;
        }
      }
    }
  } else {
    int vb2 = bid - 256;
    bool csd = vb2 >= 128;
    int rb = (vb2 & 127) * 64;
    const u16* An    = (const u16*)(ws + (csd ? WS_OC : WS_OV));
    int K            = csd ? 64 : 256;
    const u16* Wt    = (const u16*)(ws + (csd ? WS_WT_CV : WS_WT_VV));
    const float* bias= csd ? bcv : bvv;
    int dOff         = csd ? 64 : 0;

    int cgp = w & 1, sl2 = w >> 1;     // 2 colgroups(128) x 2 row-halves(32)
    int r0 = rb + sl2*32;
    int j0 = cgp * 128;

    f32x4 acc[2][8];
    #pragma unroll
    for (int s=0;s<2;s++)
      #pragma unroll
      for (int f=0; f<8; f++){ f32x4 z = {0.f,0.f,0.f,0.f}; acc[s][f] = z; }

    int nkc = K >> 5;
    for (int kc=0; kc<nkc; kc++){
      int k0 = kc*32 + q*8;
      s16x8 af0 = *(const s16x8*)(An + (r0 + c)*K + k0);
      s16x8 af1 = *(const s16x8*)(An + (r0 + 16 + c)*K + k0);
      #pragma unroll
      for (int f=0; f<8; f++){
        s16x8 bfr = *(const s16x8*)(Wt + (j0 + f*16 + c)*K + k0);
        acc[0][f] = mfma16(af0, bfr, acc[0][f]);
        acc[1][f] = mfma16(af1, bfr, acc[1][f]);
      }
    }
    // V: fragment-major [bh][t][f8][lane(qV,cV)][e], kv sigma-permuted:
    // stored (q,e): e<4 -> token q*4+e ; e>=4 -> token 16+q*4+(e-4)
    u16* vfb = (u16*)(ws + WS_VT);
    #pragma unroll
    for (int s=0;s<2;s++){
      int r = r0 + s*16 + q*4;
      int b_ = r >> 11, n = r & 2047;
      int t = n >> 5, m = n & 31;             // m&3 == 0
      int qV = (m < 16) ? (m >> 2) : ((m >> 2) - 4);
      int e0 = (m < 16) ? 0 : 4;
      #pragma unroll
      for (int f=0; f<8; f++){
        int j = j0 + f*16 + c;
        float bv_ = bias[j];
        int head = j >> 6, dd = (j & 63) + dOff;
        int f8 = dd >> 4, cV = dd & 15;
        ushort4 pk;
        pk.x = f2bf(acc[s][f][0] + bv_); pk.y = f2bf(acc[s][f][1] + bv_);
        pk.z = f2bf(acc[s][f][2] + bv_); pk.w = f2bf(acc[s][f][3] + bv_);
        *(ushort4*)(vfb + (b_*4 + head)*262144 + t*4096 + f8*512 + (qV*16 + cV)*8 + e0) = pk;
      }
    }
  }
}

// ---------------- flash attention v9: quarter-KV split, NO register cap.
// Round-7 retro: the quarter-split decomposition was correct (passed) but
// __launch_bounds__(256,4) forced a 128-reg allocation cap -> spill catastrophe.
// The double-buffered kernel naturally compiles to 128 VGPR (rounds 9-13 counters),
// which already permits 4 waves/SIMD. v9 = round-7 structure + bounds(256,2):
// grid 1024 (16 bh x 64 qb of 32 rows), wave h owns a 16-tile KV quarter,
// 2-round LDS merge tree; LDS 34.3KB x 4 blocks = 137KB <= 160KB.
__global__ __launch_bounds__(256, 2) void k_attn(char* ws){
  const u16* Qw = (const u16*)(ws + WS_Q);
  const u16* KF = (const u16*)(ws + WS_K);
  const u16* VF = (const u16*)(ws + WS_VT);
  u16* Ov = (u16*)(ws + WS_OV);
  u16* Oc = (u16*)(ws + WS_OC);
  __shared__ float mg[2][64][67];   // 34,304 B merge buffer (stride 67: conflict-free)

  int bh = blockIdx.x & 15, qb = blockIdx.x >> 4;   // qb in [0,64)
  int tid = threadIdx.x, lane = tid & 63, h = tid >> 6;
  int c = lane & 15, q = lane >> 4;
  int qr0 = qb*32;

  // Q fragments (rows qr0 + s*16 + c), read-once from global; B-operand of swapped QK^T
  s16x8 qf[2][4];
  #pragma unroll
  for (int s=0;s<2;s++)
    #pragma unroll
    for (int kc=0;kc<4;kc++)
      qf[s][kc] = *(const s16x8*)(Qw + (bh*2048 + qr0 + s*16 + c)*128 + kc*32 + q*8);

  const u16* kb = KF + bh*262144 + h*65536 + lane*8;   // quarter = 16 tiles x 4096 u16
  const u16* vb = VF + bh*262144 + h*65536 + lane*8;

  f32x4 o[2][8];
  float lsum[2] = {0.f, 0.f};
  #pragma unroll
  for (int s=0;s<2;s++)
    #pragma unroll
    for (int f8=0;f8<8;f8++){ f32x4 z = {0.f,0.f,0.f,0.f}; o[s][f8] = z; }

  s16x8 kA[2][4], vA[8], kB[2][4], vB[8];

  auto loadT = [&](s16x8 (&kf)[2][4], s16x8 (&vf)[8], int tt){
    const u16* kt = kb + tt*4096;
    const u16* vt = vb + tt*4096;
    #pragma unroll
    for (int f=0;f<2;f++)
      #pragma unroll
      for (int kc=0;kc<4;kc++)
        kf[f][kc] = *(const s16x8*)(kt + (f*4+kc)*512);
    #pragma unroll
    for (int f8=0;f8<8;f8++)
      vf[f8] = *(const s16x8*)(vt + f8*512);
  };

  auto comp = [&](const s16x8 (&kf)[2][4], const s16x8 (&vf)[8]){
    // swapped QK^T: A=K, B=Q  ->  lane (c,q) holds S[qrow=c][kv=f*16+q*4+i]
    f32x4 sfr[2][2];
    #pragma unroll
    for (int s=0;s<2;s++)
      #pragma unroll
      for (int f=0;f<2;f++){ f32x4 z = {0.f,0.f,0.f,0.f}; sfr[s][f] = z; }
    #pragma unroll
    for (int s=0;s<2;s++)
      #pragma unroll
      for (int f=0;f<2;f++)
        #pragma unroll
        for (int kc=0;kc<4;kc++)
          sfr[s][f] = mfma16(kf[f][kc], qf[s][kc], sfr[s][f]);

    #pragma unroll
    for (int s=0;s<2;s++){
      float p0 = exp2f(sfr[s][0][0]), p1 = exp2f(sfr[s][0][1]);
      float p2 = exp2f(sfr[s][0][2]), p3 = exp2f(sfr[s][0][3]);
      float p4 = exp2f(sfr[s][1][0]), p5 = exp2f(sfr[s][1][1]);
      float p6 = exp2f(sfr[s][1][2]), p7 = exp2f(sfr[s][1][3]);
      lsum[s] += ((p0+p1)+(p2+p3)) + ((p4+p5)+(p6+p7));
      union { u32 u[4]; s16x8 v; } pa;
      pa.u[0] = (u32)f2bf(p0) | ((u32)f2bf(p1) << 16);
      pa.u[1] = (u32)f2bf(p2) | ((u32)f2bf(p3) << 16);
      pa.u[2] = (u32)f2bf(p4) | ((u32)f2bf(p5) << 16);
      pa.u[3] = (u32)f2bf(p6) | ((u32)f2bf(p7) << 16);
      #pragma unroll
      for (int f8=0;f8<8;f8++)
        o[s][f8] = mfma16(pa.v, vf[f8], o[s][f8]);
    }
  };

  loadT(kA, vA, 0);
  for (int tt=0; tt<16; tt+=2){
    loadT(kB, vB, tt+1);
    comp(kA, vA);
    if (tt+2 < 16) loadT(kA, vA, tt+2);
    comp(kB, vB);
  }

  // ---- 2-round tree merge of the 4 KV quarters (f32, via LDS) ----
  __syncthreads();
  if (h == 1 || h == 3){            // round A writers
    float* d = &mg[h>>1][lane][0];
    #pragma unroll
    for (int s=0;s<2;s++)
      #pragma unroll
      for (int f8=0;f8<8;f8++)
        #pragma unroll
        for (int i=0;i<4;i++) d[(s*8+f8)*4 + i] = o[s][f8][i];
    d[64] = lsum[0]; d[65] = lsum[1];
  }
  __syncthreads();
  if (h == 0 || h == 2){            // round A readers: h0+=h1, h2+=h3
    float* d = &mg[h>>1][lane][0];
    #pragma unroll
    for (int s=0;s<2;s++)
      #pragma unroll
      for (int f8=0;f8<8;f8++)
        #pragma unroll
        for (int i=0;i<4;i++) o[s][f8][i] += d[(s*8+f8)*4 + i];
    lsum[0] += d[64]; lsum[1] += d[65];
  }
  __syncthreads();
  if (h == 2){                      // round B writer
    float* d = &mg[0][lane][0];
    #pragma unroll
    for (int s=0;s<2;s++)
      #pragma unroll
      for (int f8=0;f8<8;f8++)
        #pragma unroll
        for (int i=0;i<4;i++) d[(s*8+f8)*4 + i] = o[s][f8][i];
    d[64] = lsum[0]; d[65] = lsum[1];
  }
  __syncthreads();
  if (h == 0){                      // round B reader + epilogue
    float* d = &mg[0][lane][0];
    #pragma unroll
    for (int s=0;s<2;s++)
      #pragma unroll
      for (int f8=0;f8<8;f8++)
        #pragma unroll
        for (int i=0;i<4;i++) o[s][f8][i] += d[(s*8+f8)*4 + i];
    lsum[0] += d[64]; lsum[1] += d[65];

    // full row sums: partials live across q-groups -> reduce over lanes ^16, ^32
    #pragma unroll
    for (int s=0;s<2;s++){
      lsum[s] += __shfl_xor(lsum[s], 16);
      lsum[s] += __shfl_xor(lsum[s], 32);
    }

    int b_ = bh >> 2, hh = bh & 3;
    #pragma unroll
    for (int s=0;s<2;s++){
      float inv[4];
      #pragma unroll
      for (int i=0;i<4;i++) inv[i] = 1.0f/__shfl(lsum[s], q*4 + i);  // row q*4+i total
      #pragma unroll
      for (int f8=0;f8<8;f8++){
        int col = f8*16 + c;
        u16* dst = (col < 64) ? Ov : Oc;
        int ddim = col & 63;
        #pragma unroll
        for (int i=0;i<4;i++){
          int n = qr0 + s*16 + q*4 + i;
          dst[(b_*2048 + n)*256 + hh*64 + ddim] = f2bf(o[s][f8][i]*inv[i]);
        }
      }
    }
  }
}

// ---------------- fused output projections v4: deeper amortization (proven 185.7 config).
// bids [0,128) N=256 64-row blocks (4 slabs/wave x 64-col groups);
// [128,192) N=64 128-row blocks (2 slabs/wave).
__global__ __launch_bounds__(256) void k_out(const u16* Av, const u16* Wtv, const float* bv,
                                             const u16* Ac, const u16* Wtc, const float* bc,
                                             float* out){
  int bid = blockIdx.x;
  int tid = threadIdx.x, lane = tid & 63, w = tid >> 6;
  int c = lane & 15, q = lane >> 4;
  if (bid < 128){
    int rb = bid * 64;
    int j0 = w * 64;
    f32x4 acc[4][4];
    #pragma unroll
    for (int s=0;s<4;s++)
      #pragma unroll
      for (int f=0; f<4; f++){ f32x4 z = {0.f,0.f,0.f,0.f}; acc[s][f] = z; }
    for (int kc=0; kc<8; kc++){
      int k0 = kc*32 + q*8;
      s16x8 af[4];
      #pragma unroll
      for (int s=0;s<4;s++) af[s] = *(const s16x8*)(Av + (rb + s*16 + c)*256 + k0);
      #pragma unroll
      for (int f=0; f<4; f++){
        s16x8 bfr = *(const s16x8*)(Wtv + (j0 + f*16 + c)*256 + k0);
        #pragma unroll
        for (int s=0;s<4;s++) acc[s][f] = mfma16(af[s], bfr, acc[s][f]);
      }
    }
    #pragma unroll
    for (int f=0; f<4; f++){
      int j = j0 + f*16 + c;
      float bb = bv[j];
      #pragma unroll
      for (int s=0;s<4;s++)
        #pragma unroll
        for (int i=0;i<4;i++)
          out[(rb + s*16 + q*4 + i)*256 + j] = acc[s][f][i] + bb;
    }
  } else {
    int rb = (bid - 128) * 128;
    int r0 = rb + w*32;
    f32x4 acc[2][4];
    #pragma unroll
    for (int s=0;s<2;s++)
      #pragma unroll
      for (int f=0; f<4; f++){ f32x4 z = {0.f,0.f,0.f,0.f}; acc[s][f] = z; }
    for (int kc=0; kc<8; kc++){
      int k0 = kc*32 + q*8;
      s16x8 af0 = *(const s16x8*)(Ac + (r0 + c)*256 + k0);
      s16x8 af1 = *(const s16x8*)(Ac + (r0 + 16 + c)*256 + k0);
      #pragma unroll
      for (int f=0; f<4; f++){
        s16x8 bfr = *(const s16x8*)(Wtc + (f*16 + c)*256 + k0);
        acc[0][f] = mfma16(af0, bfr, acc[0][f]);
        acc[1][f] = mfma16(af1, bfr, acc[1][f]);
      }
    }
    float* oc = out + 2097152;
    #pragma unroll
    for (int f=0; f<4; f++){
      int j = f*16 + c;
      float bb = bc[j];
      #pragma unroll
      for (int s=0;s<2;s++)
        #pragma unroll
        for (int i=0;i<4;i++)
          oc[(r0 + s*16 + q*4 + i)*64 + j] = acc[s][f][i] + bb;
    }
  }
}

extern "C" void kernel_launch(void* const* d_in, const int* in_sizes, int n_in,
                              void* d_out, int out_size, void* d_ws, size_t ws_size,
                              hipStream_t stream){
  (void)in_sizes; (void)n_in; (void)out_size; (void)ws_size;
  const float* V    = (const float*)d_in[0];
  const float* C    = (const float*)d_in[1];
  const float* vng  = (const float*)d_in[2];
  const float* vnb  = (const float*)d_in[3];
  const float* cng  = (const float*)d_in[4];
  const float* cnb  = (const float*)d_in[5];
  const float* Wvqk = (const float*)d_in[6];
  const float* bvqk = (const float*)d_in[7];
  const float* rmsv = (const float*)d_in[8];
  const float* Wcqk = (const float*)d_in[9];
  const float* bcqk = (const float*)d_in[10];
  const float* rmsc = (const float*)d_in[11];
  const float* Wvv  = (const float*)d_in[12];
  const float* bvv  = (const float*)d_in[13];
  const float* Wcv  = (const float*)d_in[14];
  const float* bcv  = (const float*)d_in[15];
  const float* Wov  = (const float*)d_in[16];
  const float* bov  = (const float*)d_in[17];
  const float* Woc  = (const float*)d_in[18];
  const float* boc  = (const float*)d_in[19];
  char* ws = (char*)d_ws;
  float* out = (float*)d_out;

  k_prep<<<4256, 256, 0, stream>>>(V, C, vng, vnb, cng, cnb,
                                   Wvqk, Wcqk, Wvv, Wcv, Wov, Woc, ws);
  k_proj<<<512, 256, 0, stream>>>(bvqk, bcqk, rmsv, rmsc, bvv, bcv, ws);
  k_attn<<<1024, 256, 0, stream>>>(ws);
  k_out<<<192, 256, 0, stream>>>((const u16*)(ws + WS_OV), (const u16*)(ws + WS_WT_OV), bov,
                                 (const u16*)(ws + WS_OC), (const u16*)(ws + WS_WT_OC), boc,
                                 out);
}

// Round 15
// 189.922 us; speedup vs baseline: 1.0096x; 1.0056x over previous
//
#include <hip/hip_runtime.h>

typedef unsigned short u16;
typedef unsigned int   u32;
typedef short s16x8 __attribute__((ext_vector_type(8)));   // 8 x bf16 (4 VGPRs)
typedef float f32x4 __attribute__((ext_vector_type(4)));

// ---- workspace layout (bytes); total footprint 34,340,864 (proven safe) ----
#define WS_STATSV 0          // (unused)
#define WS_STATSC 65536      // (unused)
#define WS_WT_VQK 131072     // [512][256] bf16
#define WS_WT_CQK 393216     // [512][64]
#define WS_WT_VV  458752     // [256][256]
#define WS_WT_CV  589824     // [256][64]
#define WS_WT_OV  622592     // [256][256]
#define WS_WT_OC  753664     // [64][256]
#define WS_Q      786432     // [16][2048][128] bf16  (qv|qc per head; Q pre-scaled by log2e/8)
#define WS_K      9175040    // frag-major K: [16 bh][64 t][2 f][4 kc][64 lane][8] bf16 (512KB/bh)
#define WS_VT     17563648   // frag-major V: [16 bh][64 t][8 f8][64 lane][8] bf16 (sigma-permuted kv)
#define WS_OV     25952256   // [8192][256] bf16 attn-out V  (pre-attn: Vn, LN'd V bf16 [8192][256])
#define WS_OC     30146560   // [8192][256] bf16 attn-out C  (pre-attn: Cn, LN'd C bf16 [8192][64])

__device__ __forceinline__ float bf2f(u16 h){
  union { u32 u; float f; } x; x.u = ((u32)h) << 16; return x.f;
}
__device__ __forceinline__ u16 f2bf(float f){
  union { float f; u32 u; } x; x.f = f;
  u32 u = x.u; u += 0x7fffu + ((u >> 16) & 1u);
  return (u16)(u >> 16);
}
__device__ __forceinline__ f32x4 mfma16(s16x8 a, s16x8 b, f32x4 c){
  return __builtin_amdgcn_mfma_f32_16x16x32_bf16(a, b, c, 0, 0, 0);
}

// ---------------- fused: LN stats+normalize (bids 0..4095) + weight transpose (4096..4255) ----
__global__ __launch_bounds__(256) void k_prep(const float* V, const float* C,
    const float* vng, const float* vnb, const float* cng, const float* cnb,
    const float* Wvqk, const float* Wcqk, const float* Wvv, const float* Wcv,
    const float* Wov, const float* Woc, char* ws){
  int bid = blockIdx.x;
  if (bid < 4096){
    int wid = threadIdx.x >> 6, lane = threadIdx.x & 63;
    if (bid < 2048){
      int row = bid*4 + wid;
      const float4* p = (const float4*)(V + row*256);
      float4 v = p[lane];
      float s = v.x+v.y+v.z+v.w, s2 = v.x*v.x+v.y*v.y+v.z*v.z+v.w*v.w;
      for (int d=1; d<64; d<<=1){ s += __shfl_xor(s,d); s2 += __shfl_xor(s2,d); }
      float m = s*(1.0f/256.0f); float var = s2*(1.0f/256.0f) - m*m; if (var < 0.f) var = 0.f;
      float rstd = rsqrtf(var + 1e-5f), nb = -m*rstd;
      float4 gg = ((const float4*)vng)[lane];
      float4 bb = ((const float4*)vnb)[lane];
      ushort4 pk;
      pk.x = f2bf(fmaf(fmaf(v.x, rstd, nb), gg.x, bb.x));
      pk.y = f2bf(fmaf(fmaf(v.y, rstd, nb), gg.y, bb.y));
      pk.z = f2bf(fmaf(fmaf(v.z, rstd, nb), gg.z, bb.z));
      pk.w = f2bf(fmaf(fmaf(v.w, rstd, nb), gg.w, bb.w));
      *(ushort4*)((u16*)(ws + WS_OV) + row*256 + lane*4) = pk;
    } else {
      int row = (bid-2048)*4 + wid;
      float x = C[row*64 + lane];
      float s = x, s2 = x*x;
      for (int d=1; d<64; d<<=1){ s += __shfl_xor(s,d); s2 += __shfl_xor(s2,d); }
      float m = s*(1.0f/64.0f); float var = s2*(1.0f/64.0f) - m*m; if (var < 0.f) var = 0.f;
      float rstd = rsqrtf(var + 1e-5f);
      float xn = fmaf(fmaf(x, rstd, -m*rstd), cng[lane], cnb[lane]);
      ((u16*)(ws + WS_OC))[row*64 + lane] = f2bf(xn);
    }
  } else {
    int tb = bid - 4096;
    const float* src; u16* dst; int K, N, rel;
    if      (tb <  64){ src=Wvqk; dst=(u16*)(ws+WS_WT_VQK); K=256; N=512; rel=tb;     }
    else if (tb <  80){ src=Wcqk; dst=(u16*)(ws+WS_WT_CQK); K=64;  N=512; rel=tb-64;  }
    else if (tb < 112){ src=Wvv;  dst=(u16*)(ws+WS_WT_VV);  K=256; N=256; rel=tb-80;  }
    else if (tb < 120){ src=Wcv;  dst=(u16*)(ws+WS_WT_CV);  K=64;  N=256; rel=tb-112; }
    else if (tb < 152){ src=Wov;  dst=(u16*)(ws+WS_WT_OV);  K=256; N=256; rel=tb-120; }
    else              { src=Woc;  dst=(u16*)(ws+WS_WT_OC);  K=256; N=64;  rel=tb-152; }
    int e = rel*2048 + threadIdx.x*8;
    int k = e / N, n0 = e % N;
    float4 t0 = *(const float4*)(src + e);
    float4 t1 = *(const float4*)(src + e + 4);
    dst[(n0+0)*K + k] = f2bf(t0.x);
    dst[(n0+1)*K + k] = f2bf(t0.y);
    dst[(n0+2)*K + k] = f2bf(t0.z);
    dst[(n0+3)*K + k] = f2bf(t0.w);
    dst[(n0+4)*K + k] = f2bf(t1.x);
    dst[(n0+5)*K + k] = f2bf(t1.y);
    dst[(n0+6)*K + k] = f2bf(t1.z);
    dst[(n0+7)*K + k] = f2bf(t1.w);
  }
}

// ---------------- fused projections v6: deeper B-fragment amortization (proven 185.7 config).
// bids [0,128) V-qk 64-row (4 slabs/wave), [128,256) C-qk 64-row,
//      [256,384) V-v 64-row (2 slabs/wave), [384,512) C-v 64-row.
__global__ __launch_bounds__(256) void k_proj(const float* bvqk, const float* bcqk,
    const float* rmsv, const float* rmsc, const float* bvv, const float* bcv, char* ws){
  __shared__ float ssl[4][4][16];
  __shared__ u16 qst[2][2304];   // Q waves w=0,1: [head2][token16][72]
  __shared__ u16 kst[2][2048];   // K waves w=2,3: [head2][kc2][qK4][cK16][eK8]
  int bid = blockIdx.x;
  int tid = threadIdx.x, lane = tid & 63, w = tid >> 6;
  int c = lane & 15, q = lane >> 4;

  if (bid < 256){
    bool csd = bid >= 128;
    int rb = (bid & 127) * 64;
    const u16* An    = (const u16*)(ws + (csd ? WS_OC : WS_OV));   // Cn / Vn
    int K            = csd ? 64 : 256;
    const u16* Wt    = (const u16*)(ws + (csd ? WS_WT_CQK : WS_WT_VQK));
    const float* bias= csd ? bcqk : bvqk;
    const float* rms = csd ? rmsc : rmsv;
    int dOff         = csd ? 64 : 0;

    int j0 = w * 128;                 // wave = 128-col group of the 512

    f32x4 acc[4][8];
    #pragma unroll
    for (int s=0;s<4;s++)
      #pragma unroll
      for (int f=0; f<8; f++){ f32x4 z = {0.f,0.f,0.f,0.f}; acc[s][f] = z; }

    int nkc = K >> 5;
    for (int kc=0; kc<nkc; kc++){
      int k0 = kc*32 + q*8;
      s16x8 af[4];
      #pragma unroll
      for (int s=0;s<4;s++) af[s] = *(const s16x8*)(An + (rb + s*16 + c)*K + k0);
      #pragma unroll
      for (int f=0; f<8; f++){
        s16x8 bfr = *(const s16x8*)(Wt + (j0 + f*16 + c)*K + k0);
        #pragma unroll
        for (int s=0;s<4;s++) acc[s][f] = mfma16(af[s], bfr, acc[s][f]);
      }
    }

    float ss[4][4];
    #pragma unroll
    for (int s=0;s<4;s++)
      #pragma unroll
      for (int i=0;i<4;i++) ss[s][i] = 0.f;
    float rsv[8];
    #pragma unroll
    for (int f=0; f<8; f++){
      int j = j0 + f*16 + c;
      float bsv = bias[j]; rsv[f] = rms[j];
      #pragma unroll
      for (int s=0;s<4;s++)
        #pragma unroll
        for (int i=0;i<4;i++){ acc[s][f][i] += bsv; ss[s][i] += acc[s][f][i]*acc[s][f][i]; }
    }
    #pragma unroll
    for (int d=1; d<16; d<<=1){
      #pragma unroll
      for (int s=0;s<4;s++)
        #pragma unroll
        for (int i=0;i<4;i++) ss[s][i] += __shfl_xor(ss[s][i], d);
    }
    if (c == 0){
      #pragma unroll
      for (int s=0;s<4;s++)
        #pragma unroll
        for (int i=0;i<4;i++) ssl[w][s][q*4 + i] = ss[s][i];
    }
    __syncthreads();
    float rmsr[4][4];
    #pragma unroll
    for (int s=0;s<4;s++)
      #pragma unroll
      for (int i=0;i<4;i++){
        int rl = q*4 + i;
        float tot = ssl[0][s][rl] + ssl[1][s][rl] + ssl[2][s][rl] + ssl[3][s][rl];
        rmsr[s][i] = rsqrtf(tot * (1.0f/512.0f) + 1e-6f);
      }
    int b_ = rb >> 11;
    if (w < 2){
      // ---- Q: LDS bounce -> coalesced 16B stores. head = w*2 + (f>>2), dd = dOff+(f&3)*16+c
      u16* qs_ = &qst[w][0];
      u16* dstb = (u16*)(ws + WS_Q);
      const float qscale = 0.125f*1.44269504f;
      int headbase = w*2;
      #pragma unroll
      for (int s=0;s<4;s++){
        int n0g = (rb + s*16) & 2047;
        #pragma unroll
        for (int f=0; f<8; f++){
          int hl = f >> 2, dloc = (f&3)*16 + c;
          #pragma unroll
          for (int i=0;i<4;i++)
            qs_[hl*1152 + (q*4+i)*72 + dloc] = f2bf(acc[s][f][i]*rmsr[s][i]*rsv[f]*qscale);
        }
        #pragma unroll
        for (int it=0; it<4; it++){
          int hl = it>>1, token = (it&1)*8 + (lane>>3), dloc = (lane&7)*8;
          uint4 v = *(uint4*)&qs_[hl*1152 + token*72 + dloc];
          *(uint4*)(dstb + ((b_*4 + headbase + hl)*2048 + n0g + token)*128 + dOff + dloc) = v;
        }
      }
    } else {
      // ---- K: LDS bounce in exact frag-major order -> 1KB contiguous per wave-store.
      u16* ks_ = &kst[w-2][0];
      u16* kfb = (u16*)(ws + WS_K);
      int headbase = (w-2)*2;
      int kcOff = dOff >> 5;
      #pragma unroll
      for (int s=0;s<4;s++){
        int n0g = (rb + s*16) & 2047;
        int t = n0g >> 5, fK = (n0g >> 4) & 1;
        #pragma unroll
        for (int f=0; f<8; f++){
          int hl = f >> 2, ddl = (f&3)*16 + c;
          int kcl = ddl >> 5, qK = (ddl >> 3) & 3, eK = ddl & 7;
          #pragma unroll
          for (int i=0;i<4;i++)
            ks_[hl*1024 + kcl*512 + qK*128 + (q*4+i)*8 + eK]
              = f2bf(acc[s][f][i]*rmsr[s][i]*rsv[f]);
        }
        #pragma unroll
        for (int it=0; it<4; it++){
          int hl = it>>1, kcl = it&1;
          uint4 v = *(uint4*)&ks_[hl*1024 + kcl*512 + lane*8];
          *(uint4*)(kfb + (b_*4 + headbase + hl)*262144 + t*4096
                        + (fK*4 + kcOff + kcl)*512 + lane*8) = v;
        }
      }
    }
  } else {
    int vb2 = bid - 256;
    bool csd = vb2 >= 128;
    int rb = (vb2 & 127) * 64;
    const u16* An    = (const u16*)(ws + (csd ? WS_OC : WS_OV));
    int K            = csd ? 64 : 256;
    const u16* Wt    = (const u16*)(ws + (csd ? WS_WT_CV : WS_WT_VV));
    const float* bias= csd ? bcv : bvv;
    int dOff         = csd ? 64 : 0;

    int cgp = w & 1, sl2 = w >> 1;     // 2 colgroups(128) x 2 row-halves(32)
    int r0 = rb + sl2*32;
    int j0 = cgp * 128;

    f32x4 acc[2][8];
    #pragma unroll
    for (int s=0;s<2;s++)
      #pragma unroll
      for (int f=0; f<8; f++){ f32x4 z = {0.f,0.f,0.f,0.f}; acc[s][f] = z; }

    int nkc = K >> 5;
    for (int kc=0; kc<nkc; kc++){
      int k0 = kc*32 + q*8;
      s16x8 af0 = *(const s16x8*)(An + (r0 + c)*K + k0);
      s16x8 af1 = *(const s16x8*)(An + (r0 + 16 + c)*K + k0);
      #pragma unroll
      for (int f=0; f<8; f++){
        s16x8 bfr = *(const s16x8*)(Wt + (j0 + f*16 + c)*K + k0);
        acc[0][f] = mfma16(af0, bfr, acc[0][f]);
        acc[1][f] = mfma16(af1, bfr, acc[1][f]);
      }
    }
    // V: fragment-major [bh][t][f8][lane(qV,cV)][e], kv sigma-permuted:
    // stored (q,e): e<4 -> token q*4+e ; e>=4 -> token 16+q*4+(e-4)
    u16* vfb = (u16*)(ws + WS_VT);
    #pragma unroll
    for (int s=0;s<2;s++){
      int r = r0 + s*16 + q*4;
      int b_ = r >> 11, n = r & 2047;
      int t = n >> 5, m = n & 31;             // m&3 == 0
      int qV = (m < 16) ? (m >> 2) : ((m >> 2) - 4);
      int e0 = (m < 16) ? 0 : 4;
      #pragma unroll
      for (int f=0; f<8; f++){
        int j = j0 + f*16 + c;
        float bv_ = bias[j];
        int head = j >> 6, dd = (j & 63) + dOff;
        int f8 = dd >> 4, cV = dd & 15;
        ushort4 pk;
        pk.x = f2bf(acc[s][f][0] + bv_); pk.y = f2bf(acc[s][f][1] + bv_);
        pk.z = f2bf(acc[s][f][2] + bv_); pk.w = f2bf(acc[s][f][3] + bv_);
        *(ushort4*)(vfb + (b_*4 + head)*262144 + t*4096 + f8*512 + (qV*16 + cV)*8 + e0) = pk;
      }
    }
  }
}

// ---------------- flash attention v6 (proven 53.4-54.2us): zero-LDS, fragment-direct from L2.
// 512 blocks x 4 waves. Wave (g,h): g = Q-subblock (32 rows as 2x16), h = KV half.
// Register double-buffering prefetches tile t+1 while computing t; 2 blocks/CU.
// (v7 spill / v8 latency-exposure / v9 no-op occupancy: all three alternatives regressed —
// this structure is the measured optimum of the family.)
__global__ __launch_bounds__(256, 2) void k_attn(char* ws){
  const u16* Qw = (const u16*)(ws + WS_Q);
  const u16* KF = (const u16*)(ws + WS_K);
  const u16* VF = (const u16*)(ws + WS_VT);
  u16* Ov = (u16*)(ws + WS_OV);
  u16* Oc = (u16*)(ws + WS_OC);
  __shared__ float mg[2][64][67];   // 34,304 B merge buffer (stride 67: conflict-free)

  int bh = blockIdx.x & 15, qb = blockIdx.x >> 4;
  int tid = threadIdx.x, lane = tid & 63, w = tid >> 6;
  int c = lane & 15, q = lane >> 4;
  int g = w & 1, h = w >> 1;
  int qr0 = qb*64 + g*32;

  // Q fragments (rows qr0 + s*16 + c), read-once from global; B-operand of swapped QK^T
  s16x8 qf[2][4];
  #pragma unroll
  for (int s=0;s<2;s++)
    #pragma unroll
    for (int kc=0;kc<4;kc++)
      qf[s][kc] = *(const s16x8*)(Qw + (bh*2048 + qr0 + s*16 + c)*128 + kc*32 + q*8);

  const u16* kb = KF + bh*262144 + h*131072 + lane*8;   // tile stride 4096 u16
  const u16* vb = VF + bh*262144 + h*131072 + lane*8;

  f32x4 o[2][8];
  float lsum[2] = {0.f, 0.f};
  #pragma unroll
  for (int s=0;s<2;s++)
    #pragma unroll
    for (int f8=0;f8<8;f8++){ f32x4 z = {0.f,0.f,0.f,0.f}; o[s][f8] = z; }

  s16x8 kA[2][4], vA[8], kB[2][4], vB[8];

  auto loadT = [&](s16x8 (&kf)[2][4], s16x8 (&vf)[8], int tt){
    const u16* kt = kb + tt*4096;
    const u16* vt = vb + tt*4096;
    #pragma unroll
    for (int f=0;f<2;f++)
      #pragma unroll
      for (int kc=0;kc<4;kc++)
        kf[f][kc] = *(const s16x8*)(kt + (f*4+kc)*512);
    #pragma unroll
    for (int f8=0;f8<8;f8++)
      vf[f8] = *(const s16x8*)(vt + f8*512);
  };

  auto comp = [&](const s16x8 (&kf)[2][4], const s16x8 (&vf)[8]){
    // swapped QK^T: A=K, B=Q  ->  lane (c,q) holds S[qrow=c][kv=f*16+q*4+i]
    f32x4 sfr[2][2];
    #pragma unroll
    for (int s=0;s<2;s++)
      #pragma unroll
      for (int f=0;f<2;f++){ f32x4 z = {0.f,0.f,0.f,0.f}; sfr[s][f] = z; }
    #pragma unroll
    for (int s=0;s<2;s++)
      #pragma unroll
      for (int f=0;f<2;f++)
        #pragma unroll
        for (int kc=0;kc<4;kc++)
          sfr[s][f] = mfma16(kf[f][kc], qf[s][kc], sfr[s][f]);

    #pragma unroll
    for (int s=0;s<2;s++){
      float p0 = exp2f(sfr[s][0][0]), p1 = exp2f(sfr[s][0][1]);
      float p2 = exp2f(sfr[s][0][2]), p3 = exp2f(sfr[s][0][3]);
      float p4 = exp2f(sfr[s][1][0]), p5 = exp2f(sfr[s][1][1]);
      float p6 = exp2f(sfr[s][1][2]), p7 = exp2f(sfr[s][1][3]);
      lsum[s] += ((p0+p1)+(p2+p3)) + ((p4+p5)+(p6+p7));
      union { u32 u[4]; s16x8 v; } pa;
      pa.u[0] = (u32)f2bf(p0) | ((u32)f2bf(p1) << 16);
      pa.u[1] = (u32)f2bf(p2) | ((u32)f2bf(p3) << 16);
      pa.u[2] = (u32)f2bf(p4) | ((u32)f2bf(p5) << 16);
      pa.u[3] = (u32)f2bf(p6) | ((u32)f2bf(p7) << 16);
      #pragma unroll
      for (int f8=0;f8<8;f8++)
        o[s][f8] = mfma16(pa.v, vf[f8], o[s][f8]);
    }
  };

  loadT(kA, vA, 0);
  for (int tt=0; tt<32; tt+=2){
    loadT(kB, vB, tt+1);
    comp(kA, vA);
    if (tt+2 < 32) loadT(kA, vA, tt+2);
    comp(kB, vB);
  }

  // ---- merge the two KV halves (f32, via LDS) ----
  __syncthreads();
  if (h == 1){
    float* d = &mg[g][lane][0];
    #pragma unroll
    for (int s=0;s<2;s++)
      #pragma unroll
      for (int f8=0;f8<8;f8++)
        #pragma unroll
        for (int i=0;i<4;i++) d[(s*8+f8)*4 + i] = o[s][f8][i];
    d[64] = lsum[0]; d[65] = lsum[1];
  }
  __syncthreads();
  if (h == 0){
    float* d = &mg[g][lane][0];
    #pragma unroll
    for (int s=0;s<2;s++)
      #pragma unroll
      for (int f8=0;f8<8;f8++)
        #pragma unroll
        for (int i=0;i<4;i++) o[s][f8][i] += d[(s*8+f8)*4 + i];
    lsum[0] += d[64]; lsum[1] += d[65];

    // full row sums: partials live across q-groups -> reduce over lanes ^16, ^32
    #pragma unroll
    for (int s=0;s<2;s++){
      lsum[s] += __shfl_xor(lsum[s], 16);
      lsum[s] += __shfl_xor(lsum[s], 32);
    }

    int b_ = bh >> 2, hh = bh & 3;
    #pragma unroll
    for (int s=0;s<2;s++){
      float inv[4];
      #pragma unroll
      for (int i=0;i<4;i++) inv[i] = 1.0f/__shfl(lsum[s], q*4 + i);  // row q*4+i total
      #pragma unroll
      for (int f8=0;f8<8;f8++){
        int col = f8*16 + c;
        u16* dst = (col < 64) ? Ov : Oc;
        int ddim = col & 63;
        #pragma unroll
        for (int i=0;i<4;i++){
          int n = qr0 + s*16 + q*4 + i;
          dst[(b_*2048 + n)*256 + hh*64 + ddim] = f2bf(o[s][f8][i]*inv[i]);
        }
      }
    }
  }
}

// ---------------- fused output projections v4: deeper amortization (proven 185.7 config).
// bids [0,128) N=256 64-row blocks (4 slabs/wave x 64-col groups);
// [128,192) N=64 128-row blocks (2 slabs/wave).
__global__ __launch_bounds__(256) void k_out(const u16* Av, const u16* Wtv, const float* bv,
                                             const u16* Ac, const u16* Wtc, const float* bc,
                                             float* out){
  int bid = blockIdx.x;
  int tid = threadIdx.x, lane = tid & 63, w = tid >> 6;
  int c = lane & 15, q = lane >> 4;
  if (bid < 128){
    int rb = bid * 64;
    int j0 = w * 64;
    f32x4 acc[4][4];
    #pragma unroll
    for (int s=0;s<4;s++)
      #pragma unroll
      for (int f=0; f<4; f++){ f32x4 z = {0.f,0.f,0.f,0.f}; acc[s][f] = z; }
    for (int kc=0; kc<8; kc++){
      int k0 = kc*32 + q*8;
      s16x8 af[4];
      #pragma unroll
      for (int s=0;s<4;s++) af[s] = *(const s16x8*)(Av + (rb + s*16 + c)*256 + k0);
      #pragma unroll
      for (int f=0; f<4; f++){
        s16x8 bfr = *(const s16x8*)(Wtv + (j0 + f*16 + c)*256 + k0);
        #pragma unroll
        for (int s=0;s<4;s++) acc[s][f] = mfma16(af[s], bfr, acc[s][f]);
      }
    }
    #pragma unroll
    for (int f=0; f<4; f++){
      int j = j0 + f*16 + c;
      float bb = bv[j];
      #pragma unroll
      for (int s=0;s<4;s++)
        #pragma unroll
        for (int i=0;i<4;i++)
          out[(rb + s*16 + q*4 + i)*256 + j] = acc[s][f][i] + bb;
    }
  } else {
    int rb = (bid - 128) * 128;
    int r0 = rb + w*32;
    f32x4 acc[2][4];
    #pragma unroll
    for (int s=0;s<2;s++)
      #pragma unroll
      for (int f=0; f<4; f++){ f32x4 z = {0.f,0.f,0.f,0.f}; acc[s][f] = z; }
    for (int kc=0; kc<8; kc++){
      int k0 = kc*32 + q*8;
      s16x8 af0 = *(const s16x8*)(Ac + (r0 + c)*256 + k0);
      s16x8 af1 = *(const s16x8*)(Ac + (r0 + 16 + c)*256 + k0);
      #pragma unroll
      for (int f=0; f<4; f++){
        s16x8 bfr = *(const s16x8*)(Wtc + (f*16 + c)*256 + k0);
        acc[0][f] = mfma16(af0, bfr, acc[0][f]);
        acc[1][f] = mfma16(af1, bfr, acc[1][f]);
      }
    }
    float* oc = out + 2097152;
    #pragma unroll
    for (int f=0; f<4; f++){
      int j = f*16 + c;
      float bb = bc[j];
      #pragma unroll
      for (int s=0;s<2;s++)
        #pragma unroll
        for (int i=0;i<4;i++)
          oc[(r0 + s*16 + q*4 + i)*64 + j] = acc[s][f][i] + bb;
    }
  }
}

extern "C" void kernel_launch(void* const* d_in, const int* in_sizes, int n_in,
                              void* d_out, int out_size, void* d_ws, size_t ws_size,
                              hipStream_t stream){
  (void)in_sizes; (void)n_in; (void)out_size; (void)ws_size;
  const float* V    = (const float*)d_in[0];
  const float* C    = (const float*)d_in[1];
  const float* vng  = (const float*)d_in[2];
  const float* vnb  = (const float*)d_in[3];
  const float* cng  = (const float*)d_in[4];
  const float* cnb  = (const float*)d_in[5];
  const float* Wvqk = (const float*)d_in[6];
  const float* bvqk = (const float*)d_in[7];
  const float* rmsv = (const float*)d_in[8];
  const float* Wcqk = (const float*)d_in[9];
  const float* bcqk = (const float*)d_in[10];
  const float* rmsc = (const float*)d_in[11];
  const float* Wvv  = (const float*)d_in[12];
  const float* bvv  = (const float*)d_in[13];
  const float* Wcv  = (const float*)d_in[14];
  const float* bcv  = (const float*)d_in[15];
  const float* Wov  = (const float*)d_in[16];
  const float* bov  = (const float*)d_in[17];
  const float* Woc  = (const float*)d_in[18];
  const float* boc  = (const float*)d_in[19];
  char* ws = (char*)d_ws;
  float* out = (float*)d_out;

  k_prep<<<4256, 256, 0, stream>>>(V, C, vng, vnb, cng, cnb,
                                   Wvqk, Wcqk, Wvv, Wcv, Wov, Woc, ws);
  k_proj<<<512, 256, 0, stream>>>(bvqk, bcqk, rmsv, rmsc, bvv, bcv, ws);
  k_attn<<<512, 256, 0, stream>>>(ws);
  k_out<<<192, 256, 0, stream>>>((const u16*)(ws + WS_OV), (const u16*)(ws + WS_WT_OV), bov,
                                 (const u16*)(ws + WS_OC), (const u16*)(ws + WS_WT_OC), boc,
                                 out);
}

// Round 16
// 182.896 us; speedup vs baseline: 1.0484x; 1.0384x over previous
//
#include <hip/hip_runtime.h>

typedef unsigned short u16;
typedef unsigned int   u32;
typedef short s16x8 __attribute__((ext_vector_type(8)));   // 8 x bf16 (4 VGPRs)
typedef float f32x4 __attribute__((ext_vector_type(4)));

// ---- workspace layout (bytes); total footprint 34,340,864 (proven safe) ----
#define WS_STATSV 0          // (unused)
#define WS_STATSC 65536      // (unused)
#define WS_WT_VQK 131072     // [512][256] bf16
#define WS_WT_CQK 393216     // [512][64]
#define WS_WT_VV  458752     // [256][256]
#define WS_WT_CV  589824     // [256][64]
#define WS_WT_OV  622592     // [256][256]
#define WS_WT_OC  753664     // [64][256]
#define WS_Q      786432     // [16][2048][128] bf16  (qv|qc per head; Q pre-scaled by log2e/8)
#define WS_K      9175040    // frag-major K: [16 bh][64 t][2 f][4 kc][64 lane][8] bf16 (512KB/bh)
#define WS_VT     17563648   // frag-major V: [16 bh][64 t][8 f8][64 lane][8] bf16 (sigma-permuted kv)
#define WS_OV     25952256   // [8192][256] bf16 attn-out V  (pre-attn: Vn, LN'd V bf16 [8192][256])
#define WS_OC     30146560   // [8192][256] bf16 attn-out C  (pre-attn: Cn, LN'd C bf16 [8192][64])

__device__ __forceinline__ float bf2f(u16 h){
  union { u32 u; float f; } x; x.u = ((u32)h) << 16; return x.f;
}
__device__ __forceinline__ u16 f2bf(float f){
  union { float f; u32 u; } x; x.f = f;
  u32 u = x.u; u += 0x7fffu + ((u >> 16) & 1u);
  return (u16)(u >> 16);
}
__device__ __forceinline__ f32x4 mfma16(s16x8 a, s16x8 b, f32x4 c){
  return __builtin_amdgcn_mfma_f32_16x16x32_bf16(a, b, c, 0, 0, 0);
}
// Fast exp2 via the COMPILER-EMITTED v_exp_f32 (round-12 retry, hazard-safe this time):
// __builtin_amdgcn_exp2f lets the compiler's hazard recognizer insert the TRANS-op
// wait states that raw inline asm bypassed (round-12's absmax 5.5e-2 failure).
__device__ __forceinline__ float fexp2(float x){
  return __builtin_amdgcn_exp2f(x);
}

// ---------------- fused: LN stats+normalize (bids 0..4095) + weight transpose (4096..4255) ----
__global__ __launch_bounds__(256) void k_prep(const float* V, const float* C,
    const float* vng, const float* vnb, const float* cng, const float* cnb,
    const float* Wvqk, const float* Wcqk, const float* Wvv, const float* Wcv,
    const float* Wov, const float* Woc, char* ws){
  int bid = blockIdx.x;
  if (bid < 4096){
    int wid = threadIdx.x >> 6, lane = threadIdx.x & 63;
    if (bid < 2048){
      int row = bid*4 + wid;
      const float4* p = (const float4*)(V + row*256);
      float4 v = p[lane];
      float s = v.x+v.y+v.z+v.w, s2 = v.x*v.x+v.y*v.y+v.z*v.z+v.w*v.w;
      for (int d=1; d<64; d<<=1){ s += __shfl_xor(s,d); s2 += __shfl_xor(s2,d); }
      float m = s*(1.0f/256.0f); float var = s2*(1.0f/256.0f) - m*m; if (var < 0.f) var = 0.f;
      float rstd = rsqrtf(var + 1e-5f), nb = -m*rstd;
      float4 gg = ((const float4*)vng)[lane];
      float4 bb = ((const float4*)vnb)[lane];
      ushort4 pk;
      pk.x = f2bf(fmaf(fmaf(v.x, rstd, nb), gg.x, bb.x));
      pk.y = f2bf(fmaf(fmaf(v.y, rstd, nb), gg.y, bb.y));
      pk.z = f2bf(fmaf(fmaf(v.z, rstd, nb), gg.z, bb.z));
      pk.w = f2bf(fmaf(fmaf(v.w, rstd, nb), gg.w, bb.w));
      *(ushort4*)((u16*)(ws + WS_OV) + row*256 + lane*4) = pk;
    } else {
      int row = (bid-2048)*4 + wid;
      float x = C[row*64 + lane];
      float s = x, s2 = x*x;
      for (int d=1; d<64; d<<=1){ s += __shfl_xor(s,d); s2 += __shfl_xor(s2,d); }
      float m = s*(1.0f/64.0f); float var = s2*(1.0f/64.0f) - m*m; if (var < 0.f) var = 0.f;
      float rstd = rsqrtf(var + 1e-5f);
      float xn = fmaf(fmaf(x, rstd, -m*rstd), cng[lane], cnb[lane]);
      ((u16*)(ws + WS_OC))[row*64 + lane] = f2bf(xn);
    }
  } else {
    int tb = bid - 4096;
    const float* src; u16* dst; int K, N, rel;
    if      (tb <  64){ src=Wvqk; dst=(u16*)(ws+WS_WT_VQK); K=256; N=512; rel=tb;     }
    else if (tb <  80){ src=Wcqk; dst=(u16*)(ws+WS_WT_CQK); K=64;  N=512; rel=tb-64;  }
    else if (tb < 112){ src=Wvv;  dst=(u16*)(ws+WS_WT_VV);  K=256; N=256; rel=tb-80;  }
    else if (tb < 120){ src=Wcv;  dst=(u16*)(ws+WS_WT_CV);  K=64;  N=256; rel=tb-112; }
    else if (tb < 152){ src=Wov;  dst=(u16*)(ws+WS_WT_OV);  K=256; N=256; rel=tb-120; }
    else              { src=Woc;  dst=(u16*)(ws+WS_WT_OC);  K=256; N=64;  rel=tb-152; }
    int e = rel*2048 + threadIdx.x*8;
    int k = e / N, n0 = e % N;
    float4 t0 = *(const float4*)(src + e);
    float4 t1 = *(const float4*)(src + e + 4);
    dst[(n0+0)*K + k] = f2bf(t0.x);
    dst[(n0+1)*K + k] = f2bf(t0.y);
    dst[(n0+2)*K + k] = f2bf(t0.z);
    dst[(n0+3)*K + k] = f2bf(t0.w);
    dst[(n0+4)*K + k] = f2bf(t1.x);
    dst[(n0+5)*K + k] = f2bf(t1.y);
    dst[(n0+6)*K + k] = f2bf(t1.z);
    dst[(n0+7)*K + k] = f2bf(t1.w);
  }
}

// ---------------- fused projections v6: deeper B-fragment amortization (proven 185.7 config).
// bids [0,128) V-qk 64-row (4 slabs/wave), [128,256) C-qk 64-row,
//      [256,384) V-v 64-row (2 slabs/wave), [384,512) C-v 64-row.
__global__ __launch_bounds__(256) void k_proj(const float* bvqk, const float* bcqk,
    const float* rmsv, const float* rmsc, const float* bvv, const float* bcv, char* ws){
  __shared__ float ssl[4][4][16];
  __shared__ u16 qst[2][2304];   // Q waves w=0,1: [head2][token16][72]
  __shared__ u16 kst[2][2048];   // K waves w=2,3: [head2][kc2][qK4][cK16][eK8]
  int bid = blockIdx.x;
  int tid = threadIdx.x, lane = tid & 63, w = tid >> 6;
  int c = lane & 15, q = lane >> 4;

  if (bid < 256){
    bool csd = bid >= 128;
    int rb = (bid & 127) * 64;
    const u16* An    = (const u16*)(ws + (csd ? WS_OC : WS_OV));   // Cn / Vn
    int K            = csd ? 64 : 256;
    const u16* Wt    = (const u16*)(ws + (csd ? WS_WT_CQK : WS_WT_VQK));
    const float* bias= csd ? bcqk : bvqk;
    const float* rms = csd ? rmsc : rmsv;
    int dOff         = csd ? 64 : 0;

    int j0 = w * 128;                 // wave = 128-col group of the 512

    f32x4 acc[4][8];
    #pragma unroll
    for (int s=0;s<4;s++)
      #pragma unroll
      for (int f=0; f<8; f++){ f32x4 z = {0.f,0.f,0.f,0.f}; acc[s][f] = z; }

    int nkc = K >> 5;
    for (int kc=0; kc<nkc; kc++){
      int k0 = kc*32 + q*8;
      s16x8 af[4];
      #pragma unroll
      for (int s=0;s<4;s++) af[s] = *(const s16x8*)(An + (rb + s*16 + c)*K + k0);
      #pragma unroll
      for (int f=0; f<8; f++){
        s16x8 bfr = *(const s16x8*)(Wt + (j0 + f*16 + c)*K + k0);
        #pragma unroll
        for (int s=0;s<4;s++) acc[s][f] = mfma16(af[s], bfr, acc[s][f]);
      }
    }

    float ss[4][4];
    #pragma unroll
    for (int s=0;s<4;s++)
      #pragma unroll
      for (int i=0;i<4;i++) ss[s][i] = 0.f;
    float rsv[8];
    #pragma unroll
    for (int f=0; f<8; f++){
      int j = j0 + f*16 + c;
      float bsv = bias[j]; rsv[f] = rms[j];
      #pragma unroll
      for (int s=0;s<4;s++)
        #pragma unroll
        for (int i=0;i<4;i++){ acc[s][f][i] += bsv; ss[s][i] += acc[s][f][i]*acc[s][f][i]; }
    }
    #pragma unroll
    for (int d=1; d<16; d<<=1){
      #pragma unroll
      for (int s=0;s<4;s++)
        #pragma unroll
        for (int i=0;i<4;i++) ss[s][i] += __shfl_xor(ss[s][i], d);
    }
    if (c == 0){
      #pragma unroll
      for (int s=0;s<4;s++)
        #pragma unroll
        for (int i=0;i<4;i++) ssl[w][s][q*4 + i] = ss[s][i];
    }
    __syncthreads();
    float rmsr[4][4];
    #pragma unroll
    for (int s=0;s<4;s++)
      #pragma unroll
      for (int i=0;i<4;i++){
        int rl = q*4 + i;
        float tot = ssl[0][s][rl] + ssl[1][s][rl] + ssl[2][s][rl] + ssl[3][s][rl];
        rmsr[s][i] = rsqrtf(tot * (1.0f/512.0f) + 1e-6f);
      }
    int b_ = rb >> 11;
    if (w < 2){
      // ---- Q: LDS bounce -> coalesced 16B stores. head = w*2 + (f>>2), dd = dOff+(f&3)*16+c
      u16* qs_ = &qst[w][0];
      u16* dstb = (u16*)(ws + WS_Q);
      const float qscale = 0.125f*1.44269504f;
      int headbase = w*2;
      #pragma unroll
      for (int s=0;s<4;s++){
        int n0g = (rb + s*16) & 2047;
        #pragma unroll
        for (int f=0; f<8; f++){
          int hl = f >> 2, dloc = (f&3)*16 + c;
          #pragma unroll
          for (int i=0;i<4;i++)
            qs_[hl*1152 + (q*4+i)*72 + dloc] = f2bf(acc[s][f][i]*rmsr[s][i]*rsv[f]*qscale);
        }
        #pragma unroll
        for (int it=0; it<4; it++){
          int hl = it>>1, token = (it&1)*8 + (lane>>3), dloc = (lane&7)*8;
          uint4 v = *(uint4*)&qs_[hl*1152 + token*72 + dloc];
          *(uint4*)(dstb + ((b_*4 + headbase + hl)*2048 + n0g + token)*128 + dOff + dloc) = v;
        }
      }
    } else {
      // ---- K: LDS bounce in exact frag-major order -> 1KB contiguous per wave-store.
      u16* ks_ = &kst[w-2][0];
      u16* kfb = (u16*)(ws + WS_K);
      int headbase = (w-2)*2;
      int kcOff = dOff >> 5;
      #pragma unroll
      for (int s=0;s<4;s++){
        int n0g = (rb + s*16) & 2047;
        int t = n0g >> 5, fK = (n0g >> 4) & 1;
        #pragma unroll
        for (int f=0; f<8; f++){
          int hl = f >> 2, ddl = (f&3)*16 + c;
          int kcl = ddl >> 5, qK = (ddl >> 3) & 3, eK = ddl & 7;
          #pragma unroll
          for (int i=0;i<4;i++)
            ks_[hl*1024 + kcl*512 + qK*128 + (q*4+i)*8 + eK]
              = f2bf(acc[s][f][i]*rmsr[s][i]*rsv[f]);
        }
        #pragma unroll
        for (int it=0; it<4; it++){
          int hl = it>>1, kcl = it&1;
          uint4 v = *(uint4*)&ks_[hl*1024 + kcl*512 + lane*8];
          *(uint4*)(kfb + (b_*4 + headbase + hl)*262144 + t*4096
                        + (fK*4 + kcOff + kcl)*512 + lane*8) = v;
        }
      }
    }
  } else {
    int vb2 = bid - 256;
    bool csd = vb2 >= 128;
    int rb = (vb2 & 127) * 64;
    const u16* An    = (const u16*)(ws + (csd ? WS_OC : WS_OV));
    int K            = csd ? 64 : 256;
    const u16* Wt    = (const u16*)(ws + (csd ? WS_WT_CV : WS_WT_VV));
    const float* bias= csd ? bcv : bvv;
    int dOff         = csd ? 64 : 0;

    int cgp = w & 1, sl2 = w >> 1;     // 2 colgroups(128) x 2 row-halves(32)
    int r0 = rb + sl2*32;
    int j0 = cgp * 128;

    f32x4 acc[2][8];
    #pragma unroll
    for (int s=0;s<2;s++)
      #pragma unroll
      for (int f=0; f<8; f++){ f32x4 z = {0.f,0.f,0.f,0.f}; acc[s][f] = z; }

    int nkc = K >> 5;
    for (int kc=0; kc<nkc; kc++){
      int k0 = kc*32 + q*8;
      s16x8 af0 = *(const s16x8*)(An + (r0 + c)*K + k0);
      s16x8 af1 = *(const s16x8*)(An + (r0 + 16 + c)*K + k0);
      #pragma unroll
      for (int f=0; f<8; f++){
        s16x8 bfr = *(const s16x8*)(Wt + (j0 + f*16 + c)*K + k0);
        acc[0][f] = mfma16(af0, bfr, acc[0][f]);
        acc[1][f] = mfma16(af1, bfr, acc[1][f]);
      }
    }
    // V: fragment-major [bh][t][f8][lane(qV,cV)][e], kv sigma-permuted:
    // stored (q,e): e<4 -> token q*4+e ; e>=4 -> token 16+q*4+(e-4)
    u16* vfb = (u16*)(ws + WS_VT);
    #pragma unroll
    for (int s=0;s<2;s++){
      int r = r0 + s*16 + q*4;
      int b_ = r >> 11, n = r & 2047;
      int t = n >> 5, m = n & 31;             // m&3 == 0
      int qV = (m < 16) ? (m >> 2) : ((m >> 2) - 4);
      int e0 = (m < 16) ? 0 : 4;
      #pragma unroll
      for (int f=0; f<8; f++){
        int j = j0 + f*16 + c;
        float bv_ = bias[j];
        int head = j >> 6, dd = (j & 63) + dOff;
        int f8 = dd >> 4, cV = dd & 15;
        ushort4 pk;
        pk.x = f2bf(acc[s][f][0] + bv_); pk.y = f2bf(acc[s][f][1] + bv_);
        pk.z = f2bf(acc[s][f][2] + bv_); pk.w = f2bf(acc[s][f][3] + bv_);
        *(ushort4*)(vfb + (b_*4 + head)*262144 + t*4096 + f8*512 + (qV*16 + cV)*8 + e0) = pk;
      }
    }
  }
}

// ---------------- flash attention v6c: v6 structure (proven) + builtin v_exp_f32.
// 512 blocks x 4 waves. Wave (g,h): g = Q-subblock (32 rows as 2x16), h = KV half.
// Register double-buffering prefetches tile t+1 while computing t; 2 blocks/CU.
__global__ __launch_bounds__(256, 2) void k_attn(char* ws){
  const u16* Qw = (const u16*)(ws + WS_Q);
  const u16* KF = (const u16*)(ws + WS_K);
  const u16* VF = (const u16*)(ws + WS_VT);
  u16* Ov = (u16*)(ws + WS_OV);
  u16* Oc = (u16*)(ws + WS_OC);
  __shared__ float mg[2][64][67];   // 34,304 B merge buffer (stride 67: conflict-free)

  int bh = blockIdx.x & 15, qb = blockIdx.x >> 4;
  int tid = threadIdx.x, lane = tid & 63, w = tid >> 6;
  int c = lane & 15, q = lane >> 4;
  int g = w & 1, h = w >> 1;
  int qr0 = qb*64 + g*32;

  // Q fragments (rows qr0 + s*16 + c), read-once from global; B-operand of swapped QK^T
  s16x8 qf[2][4];
  #pragma unroll
  for (int s=0;s<2;s++)
    #pragma unroll
    for (int kc=0;kc<4;kc++)
      qf[s][kc] = *(const s16x8*)(Qw + (bh*2048 + qr0 + s*16 + c)*128 + kc*32 + q*8);

  const u16* kb = KF + bh*262144 + h*131072 + lane*8;   // tile stride 4096 u16
  const u16* vb = VF + bh*262144 + h*131072 + lane*8;

  f32x4 o[2][8];
  float lsum[2] = {0.f, 0.f};
  #pragma unroll
  for (int s=0;s<2;s++)
    #pragma unroll
    for (int f8=0;f8<8;f8++){ f32x4 z = {0.f,0.f,0.f,0.f}; o[s][f8] = z; }

  s16x8 kA[2][4], vA[8], kB[2][4], vB[8];

  auto loadT = [&](s16x8 (&kf)[2][4], s16x8 (&vf)[8], int tt){
    const u16* kt = kb + tt*4096;
    const u16* vt = vb + tt*4096;
    #pragma unroll
    for (int f=0;f<2;f++)
      #pragma unroll
      for (int kc=0;kc<4;kc++)
        kf[f][kc] = *(const s16x8*)(kt + (f*4+kc)*512);
    #pragma unroll
    for (int f8=0;f8<8;f8++)
      vf[f8] = *(const s16x8*)(vt + f8*512);
  };

  auto comp = [&](const s16x8 (&kf)[2][4], const s16x8 (&vf)[8]){
    // swapped QK^T: A=K, B=Q  ->  lane (c,q) holds S[qrow=c][kv=f*16+q*4+i]
    f32x4 sfr[2][2];
    #pragma unroll
    for (int s=0;s<2;s++)
      #pragma unroll
      for (int f=0;f<2;f++){ f32x4 z = {0.f,0.f,0.f,0.f}; sfr[s][f] = z; }
    #pragma unroll
    for (int s=0;s<2;s++)
      #pragma unroll
      for (int f=0;f<2;f++)
        #pragma unroll
        for (int kc=0;kc<4;kc++)
          sfr[s][f] = mfma16(kf[f][kc], qf[s][kc], sfr[s][f]);

    #pragma unroll
    for (int s=0;s<2;s++){
      float p0 = fexp2(sfr[s][0][0]), p1 = fexp2(sfr[s][0][1]);
      float p2 = fexp2(sfr[s][0][2]), p3 = fexp2(sfr[s][0][3]);
      float p4 = fexp2(sfr[s][1][0]), p5 = fexp2(sfr[s][1][1]);
      float p6 = fexp2(sfr[s][1][2]), p7 = fexp2(sfr[s][1][3]);
      lsum[s] += ((p0+p1)+(p2+p3)) + ((p4+p5)+(p6+p7));
      union { u32 u[4]; s16x8 v; } pa;
      pa.u[0] = (u32)f2bf(p0) | ((u32)f2bf(p1) << 16);
      pa.u[1] = (u32)f2bf(p2) | ((u32)f2bf(p3) << 16);
      pa.u[2] = (u32)f2bf(p4) | ((u32)f2bf(p5) << 16);
      pa.u[3] = (u32)f2bf(p6) | ((u32)f2bf(p7) << 16);
      #pragma unroll
      for (int f8=0;f8<8;f8++)
        o[s][f8] = mfma16(pa.v, vf[f8], o[s][f8]);
    }
  };

  loadT(kA, vA, 0);
  for (int tt=0; tt<32; tt+=2){
    loadT(kB, vB, tt+1);
    comp(kA, vA);
    if (tt+2 < 32) loadT(kA, vA, tt+2);
    comp(kB, vB);
  }

  // ---- merge the two KV halves (f32, via LDS) ----
  __syncthreads();
  if (h == 1){
    float* d = &mg[g][lane][0];
    #pragma unroll
    for (int s=0;s<2;s++)
      #pragma unroll
      for (int f8=0;f8<8;f8++)
        #pragma unroll
        for (int i=0;i<4;i++) d[(s*8+f8)*4 + i] = o[s][f8][i];
    d[64] = lsum[0]; d[65] = lsum[1];
  }
  __syncthreads();
  if (h == 0){
    float* d = &mg[g][lane][0];
    #pragma unroll
    for (int s=0;s<2;s++)
      #pragma unroll
      for (int f8=0;f8<8;f8++)
        #pragma unroll
        for (int i=0;i<4;i++) o[s][f8][i] += d[(s*8+f8)*4 + i];
    lsum[0] += d[64]; lsum[1] += d[65];

    // full row sums: partials live across q-groups -> reduce over lanes ^16, ^32
    #pragma unroll
    for (int s=0;s<2;s++){
      lsum[s] += __shfl_xor(lsum[s], 16);
      lsum[s] += __shfl_xor(lsum[s], 32);
    }

    int b_ = bh >> 2, hh = bh & 3;
    #pragma unroll
    for (int s=0;s<2;s++){
      float inv[4];
      #pragma unroll
      for (int i=0;i<4;i++) inv[i] = 1.0f/__shfl(lsum[s], q*4 + i);  // row q*4+i total
      #pragma unroll
      for (int f8=0;f8<8;f8++){
        int col = f8*16 + c;
        u16* dst = (col < 64) ? Ov : Oc;
        int ddim = col & 63;
        #pragma unroll
        for (int i=0;i<4;i++){
          int n = qr0 + s*16 + q*4 + i;
          dst[(b_*2048 + n)*256 + hh*64 + ddim] = f2bf(o[s][f8][i]*inv[i]);
        }
      }
    }
  }
}

// ---------------- fused output projections v4: deeper amortization (proven 185.7 config).
// bids [0,128) N=256 64-row blocks (4 slabs/wave x 64-col groups);
// [128,192) N=64 128-row blocks (2 slabs/wave).
__global__ __launch_bounds__(256) void k_out(const u16* Av, const u16* Wtv, const float* bv,
                                             const u16* Ac, const u16* Wtc, const float* bc,
                                             float* out){
  int bid = blockIdx.x;
  int tid = threadIdx.x, lane = tid & 63, w = tid >> 6;
  int c = lane & 15, q = lane >> 4;
  if (bid < 128){
    int rb = bid * 64;
    int j0 = w * 64;
    f32x4 acc[4][4];
    #pragma unroll
    for (int s=0;s<4;s++)
      #pragma unroll
      for (int f=0; f<4; f++){ f32x4 z = {0.f,0.f,0.f,0.f}; acc[s][f] = z; }
    for (int kc=0; kc<8; kc++){
      int k0 = kc*32 + q*8;
      s16x8 af[4];
      #pragma unroll
      for (int s=0;s<4;s++) af[s] = *(const s16x8*)(Av + (rb + s*16 + c)*256 + k0);
      #pragma unroll
      for (int f=0; f<4; f++){
        s16x8 bfr = *(const s16x8*)(Wtv + (j0 + f*16 + c)*256 + k0);
        #pragma unroll
        for (int s=0;s<4;s++) acc[s][f] = mfma16(af[s], bfr, acc[s][f]);
      }
    }
    #pragma unroll
    for (int f=0; f<4; f++){
      int j = j0 + f*16 + c;
      float bb = bv[j];
      #pragma unroll
      for (int s=0;s<4;s++)
        #pragma unroll
        for (int i=0;i<4;i++)
          out[(rb + s*16 + q*4 + i)*256 + j] = acc[s][f][i] + bb;
    }
  } else {
    int rb = (bid - 128) * 128;
    int r0 = rb + w*32;
    f32x4 acc[2][4];
    #pragma unroll
    for (int s=0;s<2;s++)
      #pragma unroll
      for (int f=0; f<4; f++){ f32x4 z = {0.f,0.f,0.f,0.f}; acc[s][f] = z; }
    for (int kc=0; kc<8; kc++){
      int k0 = kc*32 + q*8;
      s16x8 af0 = *(const s16x8*)(Ac + (r0 + c)*256 + k0);
      s16x8 af1 = *(const s16x8*)(Ac + (r0 + 16 + c)*256 + k0);
      #pragma unroll
      for (int f=0; f<4; f++){
        s16x8 bfr = *(const s16x8*)(Wtc + (f*16 + c)*256 + k0);
        acc[0][f] = mfma16(af0, bfr, acc[0][f]);
        acc[1][f] = mfma16(af1, bfr, acc[1][f]);
      }
    }
    float* oc = out + 2097152;
    #pragma unroll
    for (int f=0; f<4; f++){
      int j = f*16 + c;
      float bb = bc[j];
      #pragma unroll
      for (int s=0;s<2;s++)
        #pragma unroll
        for (int i=0;i<4;i++)
          oc[(r0 + s*16 + q*4 + i)*64 + j] = acc[s][f][i] + bb;
    }
  }
}

extern "C" void kernel_launch(void* const* d_in, const int* in_sizes, int n_in,
                              void* d_out, int out_size, void* d_ws, size_t ws_size,
                              hipStream_t stream){
  (void)in_sizes; (void)n_in; (void)out_size; (void)ws_size;
  const float* V    = (const float*)d_in[0];
  const float* C    = (const float*)d_in[1];
  const float* vng  = (const float*)d_in[2];
  const float* vnb  = (const float*)d_in[3];
  const float* cng  = (const float*)d_in[4];
  const float* cnb  = (const float*)d_in[5];
  const float* Wvqk = (const float*)d_in[6];
  const float* bvqk = (const float*)d_in[7];
  const float* rmsv = (const float*)d_in[8];
  const float* Wcqk = (const float*)d_in[9];
  const float* bcqk = (const float*)d_in[10];
  const float* rmsc = (const float*)d_in[11];
  const float* Wvv  = (const float*)d_in[12];
  const float* bvv  = (const float*)d_in[13];
  const float* Wcv  = (const float*)d_in[14];
  const float* bcv  = (const float*)d_in[15];
  const float* Wov  = (const float*)d_in[16];
  const float* bov  = (const float*)d_in[17];
  const float* Woc  = (const float*)d_in[18];
  const float* boc  = (const float*)d_in[19];
  char* ws = (char*)d_ws;
  float* out = (float*)d_out;

  k_prep<<<4256, 256, 0, stream>>>(V, C, vng, vnb, cng, cnb,
                                   Wvqk, Wcqk, Wvv, Wcv, Wov, Woc, ws);
  k_proj<<<512, 256, 0, stream>>>(bvqk, bcqk, rmsv, rmsc, bvv, bcv, ws);
  k_attn<<<512, 256, 0, stream>>>(ws);
  k_out<<<192, 256, 0, stream>>>((const u16*)(ws + WS_OV), (const u16*)(ws + WS_WT_OV), bov,
                                 (const u16*)(ws + WS_OC), (const u16*)(ws + WS_WT_OC), boc,
                                 out);
}